// Round 1
// baseline (504.882 us; speedup 1.0000x reference)
//
#include <hip/hip_runtime.h>

#define D 64

__global__ void degree_kernel(const int* __restrict__ src, const int* __restrict__ dst,
                              int E, int* __restrict__ deg_src, int* __restrict__ deg_dst) {
    int t = blockIdx.x * blockDim.x + threadIdx.x;
    if (t < E) {
        atomicAdd(&deg_src[src[t]], 1);
        atomicAdd(&deg_dst[dst[t]], 1);
    }
}

__global__ void norm_kernel(const int* __restrict__ deg_src, const int* __restrict__ deg_dst,
                            int n_src, int n_dst,
                            float* __restrict__ norm_src, float* __restrict__ norm_dst) {
    int t = blockIdx.x * blockDim.x + threadIdx.x;
    if (t < n_src) norm_src[t] = 1.0f / (float)max(deg_src[t], 1);
    if (t < n_dst) norm_dst[t] = 1.0f / (float)max(deg_dst[t], 1);
}

// One wave (64 lanes) = one edge; lane j handles feature element j.
// h row read is a coalesced 256B burst; atomicAdd burst into out row likewise.
__global__ void scatter_kernel(const float* __restrict__ h,
                               const int* __restrict__ src, const int* __restrict__ dst,
                               const float* __restrict__ norm_src,
                               float* __restrict__ out, int E) {
    long long t = (long long)blockIdx.x * blockDim.x + threadIdx.x;
    int e = (int)(t >> 6);
    if (e >= E) return;
    int j = (int)(t & 63);
    int s = src[e];
    int d = dst[e];
    float v = h[s * D + j] * norm_src[s];
    unsafeAtomicAdd(&out[d * D + j], v);
}

__global__ void scale_kernel(float* __restrict__ out, const float* __restrict__ norm_dst,
                             int n) {
    int t = blockIdx.x * blockDim.x + threadIdx.x;
    if (t < n) out[t] *= norm_dst[t >> 6];
}

extern "C" void kernel_launch(void* const* d_in, const int* in_sizes, int n_in,
                              void* d_out, int out_size, void* d_ws, size_t ws_size,
                              hipStream_t stream) {
    const float* h   = (const float*)d_in[0];
    const int*   src = (const int*)d_in[1];
    const int*   dst = (const int*)d_in[2];
    float* out = (float*)d_out;

    const int E     = in_sizes[1];
    const int n_src = in_sizes[0] / D;
    const int n_dst = out_size / D;

    int*   deg_src  = (int*)d_ws;
    int*   deg_dst  = deg_src + n_src;
    float* norm_src = (float*)(deg_dst + n_dst);
    float* norm_dst = norm_src + n_src;

    hipMemsetAsync(d_ws, 0, sizeof(int) * (size_t)(n_src + n_dst), stream);
    hipMemsetAsync(d_out, 0, sizeof(float) * (size_t)out_size, stream);

    degree_kernel<<<(E + 255) / 256, 256, 0, stream>>>(src, dst, E, deg_src, deg_dst);

    int nmax = n_src > n_dst ? n_src : n_dst;
    norm_kernel<<<(nmax + 255) / 256, 256, 0, stream>>>(deg_src, deg_dst, n_src, n_dst,
                                                        norm_src, norm_dst);

    long long total = (long long)E * D;
    int blocks = (int)((total + 255) / 256);
    scatter_kernel<<<blocks, 256, 0, stream>>>(h, src, dst, norm_src, out, E);

    scale_kernel<<<(out_size + 255) / 256, 256, 0, stream>>>(out, norm_dst, out_size);
}

// Round 2
// 383.675 us; speedup vs baseline: 1.3159x; 1.3159x over previous
//
#include <hip/hip_runtime.h>

#define D 64
#define SCAN_B 256

__global__ void degree_kernel(const int* __restrict__ src, const int* __restrict__ dst,
                              int E, int* __restrict__ deg_src, int* __restrict__ deg_dst) {
    int t = blockIdx.x * blockDim.x + threadIdx.x;
    if (t < E) {
        atomicAdd(&deg_src[src[t]], 1);
        atomicAdd(&deg_dst[dst[t]], 1);
    }
}

__global__ void norm_kernel(const int* __restrict__ deg_src, const int* __restrict__ deg_dst,
                            int n_src, int n_dst,
                            float* __restrict__ norm_src, float* __restrict__ norm_dst) {
    int t = blockIdx.x * blockDim.x + threadIdx.x;
    if (t < n_src) norm_src[t] = 1.0f / (float)max(deg_src[t], 1);
    if (t < n_dst) norm_dst[t] = 1.0f / (float)max(deg_dst[t], 1);
}

// ---- exclusive scan over deg_dst -> offset, 3 kernels ----
__global__ void scan1_kernel(const int* __restrict__ deg, int n,
                             int* __restrict__ out, int* __restrict__ bsums) {
    __shared__ int tmp[SCAN_B];
    int t = blockIdx.x * SCAN_B + threadIdx.x;
    int v = (t < n) ? deg[t] : 0;
    tmp[threadIdx.x] = v;
    __syncthreads();
    for (int off = 1; off < SCAN_B; off <<= 1) {
        int add = (threadIdx.x >= off) ? tmp[threadIdx.x - off] : 0;
        __syncthreads();
        tmp[threadIdx.x] += add;
        __syncthreads();
    }
    if (t < n) out[t] = tmp[threadIdx.x] - v;               // exclusive
    if (threadIdx.x == SCAN_B - 1) bsums[blockIdx.x] = tmp[threadIdx.x];
}

__global__ void scan2_kernel(int* __restrict__ bsums, int nb) {
    __shared__ int tmp[1024];
    __shared__ int carry_s;
    if (threadIdx.x == 0) carry_s = 0;
    __syncthreads();
    for (int base = 0; base < nb; base += 1024) {
        int i = base + threadIdx.x;
        int v = (i < nb) ? bsums[i] : 0;
        tmp[threadIdx.x] = v;
        __syncthreads();
        for (int off = 1; off < 1024; off <<= 1) {
            int add = (threadIdx.x >= off) ? tmp[threadIdx.x - off] : 0;
            __syncthreads();
            tmp[threadIdx.x] += add;
            __syncthreads();
        }
        int incl = tmp[threadIdx.x];
        int carry = carry_s;
        if (i < nb) bsums[i] = incl - v + carry;            // exclusive + carry
        __syncthreads();
        if (threadIdx.x == 0) carry_s = carry + tmp[1023];
        __syncthreads();
    }
}

__global__ void scan3_kernel(int* __restrict__ out, const int* __restrict__ bsums, int n) {
    int t = blockIdx.x * SCAN_B + threadIdx.x;
    if (t < n) out[t] += bsums[blockIdx.x];
}

// ---- CSR fill: bucket src indices by dst ----
__global__ void fill_kernel(const int* __restrict__ src, const int* __restrict__ dst, int E,
                            const int* __restrict__ offset, int* __restrict__ cursor,
                            int* __restrict__ csr_src) {
    int t = blockIdx.x * blockDim.x + threadIdx.x;
    if (t < E) {
        int d = dst[t];
        int pos = offset[d] + atomicAdd(&cursor[d], 1);
        csr_src[pos] = src[t];
    }
}

// ---- gather: one wave per dst row, register accumulation, single store ----
__global__ void gather_kernel(const float* __restrict__ h, const int* __restrict__ csr_src,
                              const int* __restrict__ offset, const int* __restrict__ deg_dst,
                              const float* __restrict__ norm_src,
                              const float* __restrict__ norm_dst,
                              float* __restrict__ out, int n_dst) {
    int gid = blockIdx.x * blockDim.x + threadIdx.x;
    int row = gid >> 6;
    int lane = gid & 63;
    if (row >= n_dst) return;
    int beg = offset[row];
    int end = beg + deg_dst[row];
    float acc = 0.0f;
    for (int k = beg; k < end; ++k) {
        int s = csr_src[k];
        acc += h[s * D + lane] * norm_src[s];
    }
    out[row * D + lane] = acc * norm_dst[row];
}

// ---- fallback path (round-1 atomic scatter) if ws too small ----
__global__ void scatter_kernel(const float* __restrict__ h,
                               const int* __restrict__ src, const int* __restrict__ dst,
                               const float* __restrict__ norm_src,
                               float* __restrict__ out, int E) {
    long long t = (long long)blockIdx.x * blockDim.x + threadIdx.x;
    int e = (int)(t >> 6);
    if (e >= E) return;
    int j = (int)(t & 63);
    int s = src[e];
    float v = h[s * D + j] * norm_src[s];
    unsafeAtomicAdd(&out[dst[e] * D + j], v);
}

__global__ void scale_kernel(float* __restrict__ out, const float* __restrict__ norm_dst, int n) {
    int t = blockIdx.x * blockDim.x + threadIdx.x;
    if (t < n) out[t] *= norm_dst[t >> 6];
}

extern "C" void kernel_launch(void* const* d_in, const int* in_sizes, int n_in,
                              void* d_out, int out_size, void* d_ws, size_t ws_size,
                              hipStream_t stream) {
    const float* h   = (const float*)d_in[0];
    const int*   src = (const int*)d_in[1];
    const int*   dst = (const int*)d_in[2];
    float* out = (float*)d_out;

    const int E     = in_sizes[1];
    const int n_src = in_sizes[0] / D;
    const int n_dst = out_size / D;
    const int nb    = (n_dst + SCAN_B - 1) / SCAN_B;

    // ws layout (all 4-byte elems):
    // [deg_src n_src][deg_dst n_dst][cursor n_dst][offset n_dst][bsums pad][norm_src][norm_dst][csr_src E]
    int nb_pad = ((nb + 1023) / 1024) * 1024;
    size_t need = (size_t)(n_src + 3 * (size_t)n_dst + nb_pad + n_src + n_dst) * 4 + (size_t)E * 4;

    int*   deg_src  = (int*)d_ws;
    int*   deg_dst  = deg_src + n_src;
    int*   cursor   = deg_dst + n_dst;
    int*   offset   = cursor + n_dst;
    int*   bsums    = offset + n_dst;
    float* norm_src = (float*)(bsums + nb_pad);
    float* norm_dst = norm_src + n_src;
    int*   csr_src  = (int*)(norm_dst + n_dst);

    if (ws_size < need) {
        // fallback: atomic scatter (known-correct round-1 path)
        int*   f_deg_src  = (int*)d_ws;
        int*   f_deg_dst  = f_deg_src + n_src;
        float* f_norm_src = (float*)(f_deg_dst + n_dst);
        float* f_norm_dst = f_norm_src + n_src;
        hipMemsetAsync(d_ws, 0, sizeof(int) * (size_t)(n_src + n_dst), stream);
        hipMemsetAsync(d_out, 0, sizeof(float) * (size_t)out_size, stream);
        degree_kernel<<<(E + 255) / 256, 256, 0, stream>>>(src, dst, E, f_deg_src, f_deg_dst);
        int nmax = n_src > n_dst ? n_src : n_dst;
        norm_kernel<<<(nmax + 255) / 256, 256, 0, stream>>>(f_deg_src, f_deg_dst, n_src, n_dst,
                                                            f_norm_src, f_norm_dst);
        long long total = (long long)E * D;
        scatter_kernel<<<(int)((total + 255) / 256), 256, 0, stream>>>(h, src, dst, f_norm_src, out, E);
        scale_kernel<<<(out_size + 255) / 256, 256, 0, stream>>>(out, f_norm_dst, out_size);
        return;
    }

    // zero deg_src, deg_dst, cursor (contiguous at ws start)
    hipMemsetAsync(d_ws, 0, sizeof(int) * (size_t)(n_src + 2 * (size_t)n_dst), stream);

    degree_kernel<<<(E + 255) / 256, 256, 0, stream>>>(src, dst, E, deg_src, deg_dst);

    int nmax = n_src > n_dst ? n_src : n_dst;
    norm_kernel<<<(nmax + 255) / 256, 256, 0, stream>>>(deg_src, deg_dst, n_src, n_dst,
                                                        norm_src, norm_dst);

    scan1_kernel<<<nb, SCAN_B, 0, stream>>>(deg_dst, n_dst, offset, bsums);
    scan2_kernel<<<1, 1024, 0, stream>>>(bsums, nb);
    scan3_kernel<<<nb, SCAN_B, 0, stream>>>(offset, bsums, n_dst);

    fill_kernel<<<(E + 255) / 256, 256, 0, stream>>>(src, dst, E, offset, cursor, csr_src);

    long long gthreads = (long long)n_dst * D;
    gather_kernel<<<(int)((gthreads + 255) / 256), 256, 0, stream>>>(
        h, csr_src, offset, deg_dst, norm_src, norm_dst, out, n_dst);
}

// Round 3
// 287.672 us; speedup vs baseline: 1.7551x; 1.3337x over previous
//
#include <hip/hip_runtime.h>

#define D 64
#define SCAN_B 256

__global__ void degree_kernel(const int* __restrict__ src, const int* __restrict__ dst,
                              int E, int* __restrict__ deg_src, int* __restrict__ deg_dst) {
    int t = blockIdx.x * blockDim.x + threadIdx.x;
    int base = t * 4;
    if (base + 3 < E) {
        int4 s = *(const int4*)(src + base);
        int4 d = *(const int4*)(dst + base);
        atomicAdd(&deg_src[s.x], 1); atomicAdd(&deg_src[s.y], 1);
        atomicAdd(&deg_src[s.z], 1); atomicAdd(&deg_src[s.w], 1);
        atomicAdd(&deg_dst[d.x], 1); atomicAdd(&deg_dst[d.y], 1);
        atomicAdd(&deg_dst[d.z], 1); atomicAdd(&deg_dst[d.w], 1);
    } else {
        for (int i = base; i < E; ++i) {
            atomicAdd(&deg_src[src[i]], 1);
            atomicAdd(&deg_dst[dst[i]], 1);
        }
    }
}

__global__ void norm_kernel(const int* __restrict__ deg_src, const int* __restrict__ deg_dst,
                            int n_src, int n_dst,
                            float* __restrict__ norm_src, float* __restrict__ norm_dst) {
    int t = blockIdx.x * blockDim.x + threadIdx.x;
    if (t < n_src) norm_src[t] = 1.0f / (float)max(deg_src[t], 1);
    if (t < n_dst) norm_dst[t] = 1.0f / (float)max(deg_dst[t], 1);
}

// ---- exclusive scan over deg_dst -> offset, 3 kernels ----
__global__ void scan1_kernel(const int* __restrict__ deg, int n,
                             int* __restrict__ out, int* __restrict__ bsums) {
    __shared__ int tmp[SCAN_B];
    int t = blockIdx.x * SCAN_B + threadIdx.x;
    int v = (t < n) ? deg[t] : 0;
    tmp[threadIdx.x] = v;
    __syncthreads();
    for (int off = 1; off < SCAN_B; off <<= 1) {
        int add = (threadIdx.x >= off) ? tmp[threadIdx.x - off] : 0;
        __syncthreads();
        tmp[threadIdx.x] += add;
        __syncthreads();
    }
    if (t < n) out[t] = tmp[threadIdx.x] - v;               // exclusive
    if (threadIdx.x == SCAN_B - 1) bsums[blockIdx.x] = tmp[threadIdx.x];
}

__global__ void scan2_kernel(int* __restrict__ bsums, int nb) {
    __shared__ int tmp[1024];
    __shared__ int carry_s;
    if (threadIdx.x == 0) carry_s = 0;
    __syncthreads();
    for (int base = 0; base < nb; base += 1024) {
        int i = base + threadIdx.x;
        int v = (i < nb) ? bsums[i] : 0;
        tmp[threadIdx.x] = v;
        __syncthreads();
        for (int off = 1; off < 1024; off <<= 1) {
            int add = (threadIdx.x >= off) ? tmp[threadIdx.x - off] : 0;
            __syncthreads();
            tmp[threadIdx.x] += add;
            __syncthreads();
        }
        int incl = tmp[threadIdx.x];
        int carry = carry_s;
        if (i < nb) bsums[i] = incl - v + carry;            // exclusive + carry
        __syncthreads();
        if (threadIdx.x == 0) carry_s = carry + tmp[1023];
        __syncthreads();
    }
}

__global__ void scan3_kernel(int* __restrict__ out, const int* __restrict__ bsums, int n) {
    int t = blockIdx.x * SCAN_B + threadIdx.x;
    if (t < n) out[t] += bsums[blockIdx.x];
}

// ---- CSR fill: bucket src indices by dst, int4-vectorized edge reads ----
__global__ void fill_kernel(const int* __restrict__ src, const int* __restrict__ dst, int E,
                            const int* __restrict__ offset, int* __restrict__ cursor,
                            int* __restrict__ csr_src) {
    int t = blockIdx.x * blockDim.x + threadIdx.x;
    int base = t * 4;
    if (base + 3 < E) {
        int4 s = *(const int4*)(src + base);
        int4 d = *(const int4*)(dst + base);
        int p;
        p = offset[d.x] + atomicAdd(&cursor[d.x], 1); csr_src[p] = s.x;
        p = offset[d.y] + atomicAdd(&cursor[d.y], 1); csr_src[p] = s.y;
        p = offset[d.z] + atomicAdd(&cursor[d.z], 1); csr_src[p] = s.z;
        p = offset[d.w] + atomicAdd(&cursor[d.w], 1); csr_src[p] = s.w;
    } else {
        for (int i = base; i < E; ++i) {
            int d = dst[i];
            int p = offset[d] + atomicAdd(&cursor[d], 1);
            csr_src[p] = src[i];
        }
    }
}

// ---- gather: one wave per dst row; 4 edge-groups x 16 lanes x float4 ----
// 4 edges in flight per wave-step; cross-group reduce via 2 shfl_xor steps.
__global__ void gather_kernel(const float4* __restrict__ h4, const int* __restrict__ csr_src,
                              const int* __restrict__ offset, const int* __restrict__ deg_dst,
                              const float* __restrict__ norm_src,
                              const float* __restrict__ norm_dst,
                              float4* __restrict__ out4, int n_dst) {
    int gid = blockIdx.x * blockDim.x + threadIdx.x;
    int row = gid >> 6;
    if (row >= n_dst) return;
    int lane = threadIdx.x & 63;
    int g = lane >> 4;       // edge group 0..3
    int l16 = lane & 15;     // float4 slot within the 64-float row
    int beg = offset[row];
    int end = beg + deg_dst[row];
    float ax = 0.f, ay = 0.f, az = 0.f, aw = 0.f;
    for (int k = beg + g; k < end; k += 4) {
        int s = csr_src[k];
        float ns = norm_src[s];
        float4 v = h4[s * 16 + l16];
        ax = fmaf(v.x, ns, ax);
        ay = fmaf(v.y, ns, ay);
        az = fmaf(v.z, ns, az);
        aw = fmaf(v.w, ns, aw);
    }
    ax += __shfl_xor(ax, 16); ay += __shfl_xor(ay, 16);
    az += __shfl_xor(az, 16); aw += __shfl_xor(aw, 16);
    ax += __shfl_xor(ax, 32); ay += __shfl_xor(ay, 32);
    az += __shfl_xor(az, 32); aw += __shfl_xor(aw, 32);
    if (g == 0) {
        float nd = norm_dst[row];
        float4 r;
        r.x = ax * nd; r.y = ay * nd; r.z = az * nd; r.w = aw * nd;
        out4[row * 16 + l16] = r;
    }
}

// ---- fallback path (round-1 atomic scatter) if ws too small ----
__global__ void scatter_kernel(const float* __restrict__ h,
                               const int* __restrict__ src, const int* __restrict__ dst,
                               const float* __restrict__ norm_src,
                               float* __restrict__ out, int E) {
    long long t = (long long)blockIdx.x * blockDim.x + threadIdx.x;
    int e = (int)(t >> 6);
    if (e >= E) return;
    int j = (int)(t & 63);
    int s = src[e];
    float v = h[s * D + j] * norm_src[s];
    unsafeAtomicAdd(&out[dst[e] * D + j], v);
}

__global__ void scale_kernel(float* __restrict__ out, const float* __restrict__ norm_dst, int n) {
    int t = blockIdx.x * blockDim.x + threadIdx.x;
    if (t < n) out[t] *= norm_dst[t >> 6];
}

extern "C" void kernel_launch(void* const* d_in, const int* in_sizes, int n_in,
                              void* d_out, int out_size, void* d_ws, size_t ws_size,
                              hipStream_t stream) {
    const float* h   = (const float*)d_in[0];
    const int*   src = (const int*)d_in[1];
    const int*   dst = (const int*)d_in[2];
    float* out = (float*)d_out;

    const int E     = in_sizes[1];
    const int n_src = in_sizes[0] / D;
    const int n_dst = out_size / D;
    const int nb    = (n_dst + SCAN_B - 1) / SCAN_B;

    int nb_pad = ((nb + 1023) / 1024) * 1024;
    size_t need = (size_t)(n_src + 3 * (size_t)n_dst + nb_pad + n_src + n_dst) * 4 + (size_t)E * 4;

    int*   deg_src  = (int*)d_ws;
    int*   deg_dst  = deg_src + n_src;
    int*   cursor   = deg_dst + n_dst;
    int*   offset   = cursor + n_dst;
    int*   bsums    = offset + n_dst;
    float* norm_src = (float*)(bsums + nb_pad);
    float* norm_dst = norm_src + n_src;
    int*   csr_src  = (int*)(norm_dst + n_dst);

    if (ws_size < need) {
        // fallback: atomic scatter (known-correct round-1 path)
        int*   f_deg_src  = (int*)d_ws;
        int*   f_deg_dst  = f_deg_src + n_src;
        float* f_norm_src = (float*)(f_deg_dst + n_dst);
        float* f_norm_dst = f_norm_src + n_src;
        hipMemsetAsync(d_ws, 0, sizeof(int) * (size_t)(n_src + n_dst), stream);
        hipMemsetAsync(d_out, 0, sizeof(float) * (size_t)out_size, stream);
        int eb = (E + 4 * 256 - 1) / (4 * 256);
        degree_kernel<<<eb, 256, 0, stream>>>(src, dst, E, f_deg_src, f_deg_dst);
        int nmax = n_src > n_dst ? n_src : n_dst;
        norm_kernel<<<(nmax + 255) / 256, 256, 0, stream>>>(f_deg_src, f_deg_dst, n_src, n_dst,
                                                            f_norm_src, f_norm_dst);
        long long total = (long long)E * D;
        scatter_kernel<<<(int)((total + 255) / 256), 256, 0, stream>>>(h, src, dst, f_norm_src, out, E);
        scale_kernel<<<(out_size + 255) / 256, 256, 0, stream>>>(out, f_norm_dst, out_size);
        return;
    }

    // zero deg_src, deg_dst, cursor (contiguous at ws start)
    hipMemsetAsync(d_ws, 0, sizeof(int) * (size_t)(n_src + 2 * (size_t)n_dst), stream);

    int eb4 = (E + 4 * 256 - 1) / (4 * 256);
    degree_kernel<<<eb4, 256, 0, stream>>>(src, dst, E, deg_src, deg_dst);

    int nmax = n_src > n_dst ? n_src : n_dst;
    norm_kernel<<<(nmax + 255) / 256, 256, 0, stream>>>(deg_src, deg_dst, n_src, n_dst,
                                                        norm_src, norm_dst);

    scan1_kernel<<<nb, SCAN_B, 0, stream>>>(deg_dst, n_dst, offset, bsums);
    scan2_kernel<<<1, 1024, 0, stream>>>(bsums, nb);
    scan3_kernel<<<nb, SCAN_B, 0, stream>>>(offset, bsums, n_dst);

    fill_kernel<<<eb4, 256, 0, stream>>>(src, dst, E, offset, cursor, csr_src);

    long long gthreads = (long long)n_dst * D;
    gather_kernel<<<(int)((gthreads + 255) / 256), 256, 0, stream>>>(
        (const float4*)h, csr_src, offset, deg_dst, norm_src, norm_dst,
        (float4*)out, n_dst);
}

// Round 4
// 258.109 us; speedup vs baseline: 1.9561x; 1.1145x over previous
//
#include <hip/hip_runtime.h>

#define D 64
#define SCAN_B 256
#define NXCD 8

__device__ __forceinline__ int xcd_id() {
    int x;
    asm volatile("s_getreg_b32 %0, hwreg(HW_REG_XCC_ID)" : "=s"(x));
    return x & 7;
}

// ---------- Path A: per-XCD replicated histograms, L2-local atomics ----------
// tmp word packs: rank[31:20] | xcd[19:17] | src[16:0]  (src < 131072, rank < 4096)
__global__ void hist_xcd_kernel(const int* __restrict__ src, const int* __restrict__ dst,
                                int E, int n_src, int n_dst,
                                unsigned* repl_src, unsigned* repl_dst,
                                unsigned* __restrict__ tmp) {
    int x = xcd_id();
    unsigned* rs = repl_src + (size_t)x * n_src;
    unsigned* rd = repl_dst + (size_t)x * n_dst;
    int t = blockIdx.x * blockDim.x + threadIdx.x;
    int base = t * 4;
    unsigned xb = ((unsigned)x) << 17;
    if (base + 3 < E) {
        int4 s4 = *(const int4*)(src + base);
        int4 d4 = *(const int4*)(dst + base);
        unsigned r0 = __hip_atomic_fetch_add(&rd[d4.x], 1u, __ATOMIC_RELAXED, __HIP_MEMORY_SCOPE_WORKGROUP);
        unsigned r1 = __hip_atomic_fetch_add(&rd[d4.y], 1u, __ATOMIC_RELAXED, __HIP_MEMORY_SCOPE_WORKGROUP);
        unsigned r2 = __hip_atomic_fetch_add(&rd[d4.z], 1u, __ATOMIC_RELAXED, __HIP_MEMORY_SCOPE_WORKGROUP);
        unsigned r3 = __hip_atomic_fetch_add(&rd[d4.w], 1u, __ATOMIC_RELAXED, __HIP_MEMORY_SCOPE_WORKGROUP);
        __hip_atomic_fetch_add(&rs[s4.x], 1u, __ATOMIC_RELAXED, __HIP_MEMORY_SCOPE_WORKGROUP);
        __hip_atomic_fetch_add(&rs[s4.y], 1u, __ATOMIC_RELAXED, __HIP_MEMORY_SCOPE_WORKGROUP);
        __hip_atomic_fetch_add(&rs[s4.z], 1u, __ATOMIC_RELAXED, __HIP_MEMORY_SCOPE_WORKGROUP);
        __hip_atomic_fetch_add(&rs[s4.w], 1u, __ATOMIC_RELAXED, __HIP_MEMORY_SCOPE_WORKGROUP);
        uint4 o;
        o.x = (r0 << 20) | xb | (unsigned)s4.x;
        o.y = (r1 << 20) | xb | (unsigned)s4.y;
        o.z = (r2 << 20) | xb | (unsigned)s4.z;
        o.w = (r3 << 20) | xb | (unsigned)s4.w;
        *(uint4*)(tmp + base) = o;
    } else {
        for (int i = base; i < E; ++i) {
            int s = src[i], d = dst[i];
            unsigned r = __hip_atomic_fetch_add(&rd[d], 1u, __ATOMIC_RELAXED, __HIP_MEMORY_SCOPE_WORKGROUP);
            __hip_atomic_fetch_add(&rs[s], 1u, __ATOMIC_RELAXED, __HIP_MEMORY_SCOPE_WORKGROUP);
            tmp[i] = (r << 20) | xb | (unsigned)s;
        }
    }
}

// Sum replicas; repl_dst becomes per-XCD exclusive prefix (pre[x][d]) in place;
// norm_src aliases repl_src plane 0 (per-thread read-all-then-write, no hazard).
__global__ void reduce_kernel(unsigned* repl_src, unsigned* repl_dst,
                              int n_src, int n_dst,
                              int* __restrict__ deg_dst, float* norm_src) {
    int i = blockIdx.x * blockDim.x + threadIdx.x;
    if (i < n_dst) {
        unsigned s = 0;
        #pragma unroll
        for (int x = 0; x < NXCD; ++x) {
            unsigned t = repl_dst[(size_t)x * n_dst + i];
            repl_dst[(size_t)x * n_dst + i] = s;
            s += t;
        }
        deg_dst[i] = (int)s;
    }
    if (i < n_src) {
        unsigned s = 0;
        #pragma unroll
        for (int x = 0; x < NXCD; ++x) s += repl_src[(size_t)x * n_src + i];
        int si = (int)s; if (si < 1) si = 1;
        norm_src[i] = 1.0f / (float)si;
    }
}

// ---- exclusive scan (3 kernels) ----
__global__ void scan1_kernel(const int* __restrict__ deg, int n,
                             int* __restrict__ out, int* __restrict__ bsums) {
    __shared__ int tmp[SCAN_B];
    int t = blockIdx.x * SCAN_B + threadIdx.x;
    int v = (t < n) ? deg[t] : 0;
    tmp[threadIdx.x] = v;
    __syncthreads();
    for (int off = 1; off < SCAN_B; off <<= 1) {
        int add = (threadIdx.x >= off) ? tmp[threadIdx.x - off] : 0;
        __syncthreads();
        tmp[threadIdx.x] += add;
        __syncthreads();
    }
    if (t < n) out[t] = tmp[threadIdx.x] - v;
    if (threadIdx.x == SCAN_B - 1) bsums[blockIdx.x] = tmp[threadIdx.x];
}

__global__ void scan2_kernel(int* __restrict__ bsums, int nb) {
    __shared__ int tmp[1024];
    __shared__ int carry_s;
    if (threadIdx.x == 0) carry_s = 0;
    __syncthreads();
    for (int base = 0; base < nb; base += 1024) {
        int i = base + threadIdx.x;
        int v = (i < nb) ? bsums[i] : 0;
        tmp[threadIdx.x] = v;
        __syncthreads();
        for (int off = 1; off < 1024; off <<= 1) {
            int add = (threadIdx.x >= off) ? tmp[threadIdx.x - off] : 0;
            __syncthreads();
            tmp[threadIdx.x] += add;
            __syncthreads();
        }
        int incl = tmp[threadIdx.x];
        int carry = carry_s;
        if (i < nb) bsums[i] = incl - v + carry;
        __syncthreads();
        if (threadIdx.x == 0) carry_s = carry + tmp[1023];
        __syncthreads();
    }
}

__global__ void scan3_kernel(int* __restrict__ out, const int* __restrict__ bsums, int n) {
    int t = blockIdx.x * SCAN_B + threadIdx.x;
    if (t < n) out[t] += bsums[blockIdx.x];
}

// atomic-free CSR placement from packed tmp
__global__ void fill2_kernel(const int* __restrict__ dst, const unsigned* __restrict__ tmp, int E,
                             const int* __restrict__ offset, const unsigned* __restrict__ pre,
                             int n_dst, int* __restrict__ csr_src) {
    int t = blockIdx.x * blockDim.x + threadIdx.x;
    int base = t * 4;
    if (base + 3 < E) {
        int4 d4 = *(const int4*)(dst + base);
        uint4 v4 = *(const uint4*)(tmp + base);
        {
            unsigned v = v4.x; int d = d4.x;
            csr_src[offset[d] + (int)pre[(size_t)((v >> 17) & 7) * n_dst + d] + (int)(v >> 20)] = (int)(v & 0x1FFFF);
        }
        {
            unsigned v = v4.y; int d = d4.y;
            csr_src[offset[d] + (int)pre[(size_t)((v >> 17) & 7) * n_dst + d] + (int)(v >> 20)] = (int)(v & 0x1FFFF);
        }
        {
            unsigned v = v4.z; int d = d4.z;
            csr_src[offset[d] + (int)pre[(size_t)((v >> 17) & 7) * n_dst + d] + (int)(v >> 20)] = (int)(v & 0x1FFFF);
        }
        {
            unsigned v = v4.w; int d = d4.w;
            csr_src[offset[d] + (int)pre[(size_t)((v >> 17) & 7) * n_dst + d] + (int)(v >> 20)] = (int)(v & 0x1FFFF);
        }
    } else {
        for (int i = base; i < E; ++i) {
            unsigned v = tmp[i]; int d = dst[i];
            csr_src[offset[d] + (int)pre[(size_t)((v >> 17) & 7) * n_dst + d] + (int)(v >> 20)] = (int)(v & 0x1FFFF);
        }
    }
}

// ---- gather: one wave per dst row; 4 edge-groups x 16 lanes x float4 ----
__global__ void gather_kernel(const float4* __restrict__ h4, const int* __restrict__ csr_src,
                              const int* __restrict__ offset, const int* __restrict__ deg_dst,
                              const float* __restrict__ norm_src,
                              float4* __restrict__ out4, int n_dst) {
    int gid = blockIdx.x * blockDim.x + threadIdx.x;
    int row = gid >> 6;
    if (row >= n_dst) return;
    int lane = threadIdx.x & 63;
    int g = lane >> 4;
    int l16 = lane & 15;
    int beg = offset[row];
    int deg = deg_dst[row];
    int end = beg + deg;
    float ax = 0.f, ay = 0.f, az = 0.f, aw = 0.f;
    for (int k = beg + g; k < end; k += 4) {
        int s = csr_src[k];
        float ns = norm_src[s];
        float4 v = h4[s * 16 + l16];
        ax = fmaf(v.x, ns, ax);
        ay = fmaf(v.y, ns, ay);
        az = fmaf(v.z, ns, az);
        aw = fmaf(v.w, ns, aw);
    }
    ax += __shfl_xor(ax, 16); ay += __shfl_xor(ay, 16);
    az += __shfl_xor(az, 16); aw += __shfl_xor(aw, 16);
    ax += __shfl_xor(ax, 32); ay += __shfl_xor(ay, 32);
    az += __shfl_xor(az, 32); aw += __shfl_xor(aw, 32);
    if (g == 0) {
        int dg = deg < 1 ? 1 : deg;
        float nd = 1.0f / (float)dg;
        float4 r;
        r.x = ax * nd; r.y = ay * nd; r.z = az * nd; r.w = aw * nd;
        out4[row * 16 + l16] = r;
    }
}

// ---------- Path B/C fallback kernels (device-scope atomics) ----------
__global__ void degree_kernel(const int* __restrict__ src, const int* __restrict__ dst,
                              int E, int* __restrict__ deg_src, int* __restrict__ deg_dst) {
    int t = blockIdx.x * blockDim.x + threadIdx.x;
    int base = t * 4;
    if (base + 3 < E) {
        int4 s = *(const int4*)(src + base);
        int4 d = *(const int4*)(dst + base);
        atomicAdd(&deg_src[s.x], 1); atomicAdd(&deg_src[s.y], 1);
        atomicAdd(&deg_src[s.z], 1); atomicAdd(&deg_src[s.w], 1);
        atomicAdd(&deg_dst[d.x], 1); atomicAdd(&deg_dst[d.y], 1);
        atomicAdd(&deg_dst[d.z], 1); atomicAdd(&deg_dst[d.w], 1);
    } else {
        for (int i = base; i < E; ++i) {
            atomicAdd(&deg_src[src[i]], 1);
            atomicAdd(&deg_dst[dst[i]], 1);
        }
    }
}

__global__ void norm_src_kernel(const int* __restrict__ deg_src, int n_src,
                                float* __restrict__ norm_src) {
    int t = blockIdx.x * blockDim.x + threadIdx.x;
    if (t < n_src) {
        int s = deg_src[t]; if (s < 1) s = 1;
        norm_src[t] = 1.0f / (float)s;
    }
}

__global__ void fill_kernel(const int* __restrict__ src, const int* __restrict__ dst, int E,
                            const int* __restrict__ offset, int* __restrict__ cursor,
                            int* __restrict__ csr_src) {
    int t = blockIdx.x * blockDim.x + threadIdx.x;
    int base = t * 4;
    if (base + 3 < E) {
        int4 s = *(const int4*)(src + base);
        int4 d = *(const int4*)(dst + base);
        int p;
        p = offset[d.x] + atomicAdd(&cursor[d.x], 1); csr_src[p] = s.x;
        p = offset[d.y] + atomicAdd(&cursor[d.y], 1); csr_src[p] = s.y;
        p = offset[d.z] + atomicAdd(&cursor[d.z], 1); csr_src[p] = s.z;
        p = offset[d.w] + atomicAdd(&cursor[d.w], 1); csr_src[p] = s.w;
    } else {
        for (int i = base; i < E; ++i) {
            int d = dst[i];
            int p = offset[d] + atomicAdd(&cursor[d], 1);
            csr_src[p] = src[i];
        }
    }
}

__global__ void scatter_kernel(const float* __restrict__ h,
                               const int* __restrict__ src, const int* __restrict__ dst,
                               const float* __restrict__ norm_src,
                               float* __restrict__ out, int E) {
    long long t = (long long)blockIdx.x * blockDim.x + threadIdx.x;
    int e = (int)(t >> 6);
    if (e >= E) return;
    int j = (int)(t & 63);
    int s = src[e];
    float v = h[s * D + j] * norm_src[s];
    unsafeAtomicAdd(&out[dst[e] * D + j], v);
}

__global__ void scale_kernel(float* __restrict__ out, const int* __restrict__ deg_dst, int n) {
    int t = blockIdx.x * blockDim.x + threadIdx.x;
    if (t < n) {
        int dg = deg_dst[t >> 6]; if (dg < 1) dg = 1;
        out[t] *= 1.0f / (float)dg;
    }
}

extern "C" void kernel_launch(void* const* d_in, const int* in_sizes, int n_in,
                              void* d_out, int out_size, void* d_ws, size_t ws_size,
                              hipStream_t stream) {
    const float* h   = (const float*)d_in[0];
    const int*   src = (const int*)d_in[1];
    const int*   dst = (const int*)d_in[2];
    float* out = (float*)d_out;

    const int E     = in_sizes[1];
    const int n_src = in_sizes[0] / D;
    const int n_dst = out_size / D;
    const int nb    = (n_dst + SCAN_B - 1) / SCAN_B;
    const int nb_pad = ((nb + 1023) / 1024) * 1024;
    const int eb4 = (E + 4 * 256 - 1) / (4 * 256);
    const int nblk = ((n_src > n_dst ? n_src : n_dst) + 255) / 256;

    // ---- Path A layout ----
    size_t needA = ((size_t)NXCD * (n_src + n_dst) + 2 * (size_t)n_dst + nb_pad) * 4
                 + (size_t)E * 8;
    // ---- Path B layout ----
    size_t needB = ((size_t)n_src * 2 + (size_t)n_dst * 3 + nb_pad) * 4 + (size_t)E * 4;

    if (ws_size >= needA) {
        unsigned* repl_src = (unsigned*)d_ws;                 // 8*n_src
        unsigned* repl_dst = repl_src + (size_t)NXCD * n_src; // 8*n_dst
        int* deg_dst = (int*)(repl_dst + (size_t)NXCD * n_dst);
        int* offset  = deg_dst + n_dst;
        int* bsums   = offset + n_dst;
        unsigned* tmp = (unsigned*)(bsums + nb_pad);          // E
        int* csr_src = (int*)(tmp + E);                       // E
        float* norm_src = (float*)repl_src;                   // alias plane 0 (after reduce)

        hipMemsetAsync(d_ws, 0, (size_t)NXCD * (n_src + n_dst) * 4, stream);

        hist_xcd_kernel<<<eb4, 256, 0, stream>>>(src, dst, E, n_src, n_dst,
                                                 repl_src, repl_dst, tmp);
        reduce_kernel<<<nblk, 256, 0, stream>>>(repl_src, repl_dst, n_src, n_dst,
                                                deg_dst, norm_src);
        scan1_kernel<<<nb, SCAN_B, 0, stream>>>(deg_dst, n_dst, offset, bsums);
        scan2_kernel<<<1, 1024, 0, stream>>>(bsums, nb);
        scan3_kernel<<<nb, SCAN_B, 0, stream>>>(offset, bsums, n_dst);
        fill2_kernel<<<eb4, 256, 0, stream>>>(dst, tmp, E, offset, repl_dst, n_dst, csr_src);

        long long gthreads = (long long)n_dst * D;
        gather_kernel<<<(int)((gthreads + 255) / 256), 256, 0, stream>>>(
            (const float4*)h, csr_src, offset, deg_dst, norm_src, (float4*)out, n_dst);
        return;
    }

    if (ws_size >= needB) {
        int* deg_src = (int*)d_ws;
        int* deg_dst = deg_src + n_src;
        int* cursor  = deg_dst + n_dst;
        int* offset  = cursor + n_dst;
        int* bsums   = offset + n_dst;
        float* norm_src = (float*)(bsums + nb_pad);
        int* csr_src = (int*)(norm_src + n_src);

        hipMemsetAsync(d_ws, 0, sizeof(int) * (size_t)(n_src + 2 * (size_t)n_dst), stream);
        degree_kernel<<<eb4, 256, 0, stream>>>(src, dst, E, deg_src, deg_dst);
        norm_src_kernel<<<nblk, 256, 0, stream>>>(deg_src, n_src, norm_src);
        scan1_kernel<<<nb, SCAN_B, 0, stream>>>(deg_dst, n_dst, offset, bsums);
        scan2_kernel<<<1, 1024, 0, stream>>>(bsums, nb);
        scan3_kernel<<<nb, SCAN_B, 0, stream>>>(offset, bsums, n_dst);
        fill_kernel<<<eb4, 256, 0, stream>>>(src, dst, E, offset, cursor, csr_src);
        long long gthreads = (long long)n_dst * D;
        gather_kernel<<<(int)((gthreads + 255) / 256), 256, 0, stream>>>(
            (const float4*)h, csr_src, offset, deg_dst, norm_src, (float4*)out, n_dst);
        return;
    }

    // minimal fallback: atomic scatter
    {
        int* deg_src = (int*)d_ws;
        int* deg_dst = deg_src + n_src;
        float* norm_src = (float*)(deg_dst + n_dst);
        hipMemsetAsync(d_ws, 0, sizeof(int) * (size_t)(n_src + n_dst), stream);
        hipMemsetAsync(d_out, 0, sizeof(float) * (size_t)out_size, stream);
        degree_kernel<<<eb4, 256, 0, stream>>>(src, dst, E, deg_src, deg_dst);
        norm_src_kernel<<<nblk, 256, 0, stream>>>(deg_src, n_src, norm_src);
        long long total = (long long)E * D;
        scatter_kernel<<<(int)((total + 255) / 256), 256, 0, stream>>>(h, src, dst, norm_src, out, E);
        scale_kernel<<<(out_size + 255) / 256, 256, 0, stream>>>(out, deg_dst, out_size);
    }
}

// Round 5
// 162.049 us; speedup vs baseline: 3.1156x; 1.5928x over previous
//
#include <hip/hip_runtime.h>

#define D 64
#define SCAN_B 256
#define NBUCK 1024   // coarse buckets: key >> 7
#define BSH 7
#define BMSK 127
#define NCHUNK 512   // edge chunks for count/scatter passes

// ---------------- Path A: atomic-free two-level counting sort ----------------

// P1: per (bucket, chunk) counts for dst and src, bucket-major layout.
__global__ void p1_count(const int* __restrict__ src, const int* __restrict__ dst, int E,
                         int epc, int* __restrict__ cnt) {
    __shared__ int cd[NBUCK], cs[NBUCK];
    int c = blockIdx.x;
    for (int i = threadIdx.x; i < NBUCK; i += 256) { cd[i] = 0; cs[i] = 0; }
    __syncthreads();
    int beg = c * epc, end = min(E, beg + epc);
    for (int i = beg + threadIdx.x; i < end; i += 256) {
        atomicAdd(&cd[((unsigned)dst[i]) >> BSH], 1);
        atomicAdd(&cs[((unsigned)src[i]) >> BSH], 1);
    }
    __syncthreads();
    for (int b = threadIdx.x; b < NBUCK; b += 256) {
        cnt[(size_t)b * NCHUNK + c] = cd[b];
        cnt[(size_t)(NBUCK + b) * NCHUNK + c] = cs[b];
    }
}

// ---- exclusive scan (3 kernels, supports n up to ~4M) ----
__global__ void scan1_kernel(const int* __restrict__ deg, int n,
                             int* __restrict__ out, int* __restrict__ bsums) {
    __shared__ int tmp[SCAN_B];
    int t = blockIdx.x * SCAN_B + threadIdx.x;
    int v = (t < n) ? deg[t] : 0;
    tmp[threadIdx.x] = v;
    __syncthreads();
    for (int off = 1; off < SCAN_B; off <<= 1) {
        int add = (threadIdx.x >= off) ? tmp[threadIdx.x - off] : 0;
        __syncthreads();
        tmp[threadIdx.x] += add;
        __syncthreads();
    }
    if (t < n) out[t] = tmp[threadIdx.x] - v;
    if (threadIdx.x == SCAN_B - 1) bsums[blockIdx.x] = tmp[threadIdx.x];
}

__global__ void scan2_kernel(int* __restrict__ bsums, int nb) {
    __shared__ int tmp[1024];
    __shared__ int carry_s;
    if (threadIdx.x == 0) carry_s = 0;
    __syncthreads();
    for (int base = 0; base < nb; base += 1024) {
        int i = base + threadIdx.x;
        int v = (i < nb) ? bsums[i] : 0;
        tmp[threadIdx.x] = v;
        __syncthreads();
        for (int off = 1; off < 1024; off <<= 1) {
            int add = (threadIdx.x >= off) ? tmp[threadIdx.x - off] : 0;
            __syncthreads();
            tmp[threadIdx.x] += add;
            __syncthreads();
        }
        int incl = tmp[threadIdx.x];
        int carry = carry_s;
        if (i < nb) bsums[i] = incl - v + carry;
        __syncthreads();
        if (threadIdx.x == 0) carry_s = carry + tmp[1023];
        __syncthreads();
    }
}

__global__ void scan3_kernel(int* __restrict__ out, const int* __restrict__ bsums, int n) {
    int t = blockIdx.x * SCAN_B + threadIdx.x;
    if (t < n) out[t] += bsums[blockIdx.x];
}

// P2: scatter edges into bucket-partitioned arrays via LDS cursors.
__global__ void p2_scatter(const int* __restrict__ src, const int* __restrict__ dst, int E,
                           int epc, const int* __restrict__ base,
                           int* __restrict__ packD, unsigned char* __restrict__ srtS) {
    __shared__ int curD[NBUCK], curS[NBUCK];
    int c = blockIdx.x;
    for (int b = threadIdx.x; b < NBUCK; b += 256) {
        curD[b] = base[(size_t)b * NCHUNK + c];
        curS[b] = base[(size_t)(NBUCK + b) * NCHUNK + c] - E;
    }
    __syncthreads();
    int beg = c * epc, end = min(E, beg + epc);
    for (int i = beg + threadIdx.x; i < end; i += 256) {
        int d = dst[i], s = src[i];
        int pd = atomicAdd(&curD[((unsigned)d) >> BSH], 1);
        packD[pd] = (s << BSH) | (d & BMSK);
        int ps = atomicAdd(&curS[((unsigned)s) >> BSH], 1);
        srtS[ps] = (unsigned char)(s & BMSK);
    }
}

// P3: per dst-bucket: 128-bin LDS histogram + scan -> deg, offset, csr placement.
__global__ void p3_place(const int* __restrict__ packD, const int* __restrict__ base,
                         int E, int n_dst,
                         int* __restrict__ csr, int* __restrict__ offset,
                         int* __restrict__ deg) {
    __shared__ int hist[128];
    __shared__ int excl[128];
    int b = blockIdx.x;
    int beg = base[(size_t)b * NCHUNK];
    int end = (b + 1 < NBUCK) ? base[(size_t)(b + 1) * NCHUNK] : E;
    if (threadIdx.x < 128) hist[threadIdx.x] = 0;
    __syncthreads();
    for (int i = beg + threadIdx.x; i < end; i += 256)
        atomicAdd(&hist[packD[i] & BMSK], 1);
    __syncthreads();
    if (threadIdx.x < 128) excl[threadIdx.x] = hist[threadIdx.x];
    __syncthreads();
    for (int off = 1; off < 128; off <<= 1) {
        int v = 0;
        if (threadIdx.x < 128 && threadIdx.x >= off) v = excl[threadIdx.x - off];
        __syncthreads();
        if (threadIdx.x < 128) excl[threadIdx.x] += v;
        __syncthreads();
    }
    // excl now holds inclusive sums
    int h = 0;
    if (threadIdx.x < 128) h = hist[threadIdx.x];
    __syncthreads();
    if (threadIdx.x < 128) {
        int ex = excl[threadIdx.x] - h;
        int dbin = b * 128 + threadIdx.x;
        if (dbin < n_dst) {
            deg[dbin] = h;
            offset[dbin] = beg + ex;
        }
        hist[threadIdx.x] = ex;   // becomes cursor
    }
    __syncthreads();
    for (int i = beg + threadIdx.x; i < end; i += 256) {
        int v = packD[i];
        int pos = beg + atomicAdd(&hist[v & BMSK], 1);
        csr[pos] = v >> BSH;
    }
}

// P3': per src-bucket: 128-bin LDS histogram -> norm_src.
__global__ void p3s_norm(const unsigned char* __restrict__ srtS, const int* __restrict__ base,
                         int E, int n_src, float* __restrict__ norm_src) {
    __shared__ int hist[128];
    int b = blockIdx.x;
    int beg = base[(size_t)(NBUCK + b) * NCHUNK] - E;
    int end = (b + 1 < NBUCK) ? base[(size_t)(NBUCK + b + 1) * NCHUNK] - E : E;
    if (threadIdx.x < 128) hist[threadIdx.x] = 0;
    __syncthreads();
    for (int i = beg + threadIdx.x; i < end; i += 256)
        atomicAdd(&hist[srtS[i]], 1);
    __syncthreads();
    if (threadIdx.x < 128) {
        int sbin = b * 128 + threadIdx.x;
        if (sbin < n_src) {
            int h = hist[threadIdx.x]; if (h < 1) h = 1;
            norm_src[sbin] = 1.0f / (float)h;
        }
    }
}

// ---- gather: one wave per dst row; 4 edge-groups x 16 lanes x float4 ----
__global__ void gather_kernel(const float4* __restrict__ h4, const int* __restrict__ csr_src,
                              const int* __restrict__ offset, const int* __restrict__ deg_dst,
                              const float* __restrict__ norm_src,
                              float4* __restrict__ out4, int n_dst) {
    int gid = blockIdx.x * blockDim.x + threadIdx.x;
    int row = gid >> 6;
    if (row >= n_dst) return;
    int lane = threadIdx.x & 63;
    int g = lane >> 4;
    int l16 = lane & 15;
    int beg = offset[row];
    int deg = deg_dst[row];
    int end = beg + deg;
    float ax = 0.f, ay = 0.f, az = 0.f, aw = 0.f;
    for (int k = beg + g; k < end; k += 4) {
        int s = csr_src[k];
        float ns = norm_src[s];
        float4 v = h4[s * 16 + l16];
        ax = fmaf(v.x, ns, ax);
        ay = fmaf(v.y, ns, ay);
        az = fmaf(v.z, ns, az);
        aw = fmaf(v.w, ns, aw);
    }
    ax += __shfl_xor(ax, 16); ay += __shfl_xor(ay, 16);
    az += __shfl_xor(az, 16); aw += __shfl_xor(aw, 16);
    ax += __shfl_xor(ax, 32); ay += __shfl_xor(ay, 32);
    az += __shfl_xor(az, 32); aw += __shfl_xor(aw, 32);
    if (g == 0) {
        int dg = deg < 1 ? 1 : deg;
        float nd = 1.0f / (float)dg;
        float4 r;
        r.x = ax * nd; r.y = ay * nd; r.z = az * nd; r.w = aw * nd;
        out4[row * 16 + l16] = r;
    }
}

// ---------------- Fallback kernels (paths B/C) ----------------
__global__ void degree_kernel(const int* __restrict__ src, const int* __restrict__ dst,
                              int E, int* __restrict__ deg_src, int* __restrict__ deg_dst) {
    int t = blockIdx.x * blockDim.x + threadIdx.x;
    int base = t * 4;
    if (base + 3 < E) {
        int4 s = *(const int4*)(src + base);
        int4 d = *(const int4*)(dst + base);
        atomicAdd(&deg_src[s.x], 1); atomicAdd(&deg_src[s.y], 1);
        atomicAdd(&deg_src[s.z], 1); atomicAdd(&deg_src[s.w], 1);
        atomicAdd(&deg_dst[d.x], 1); atomicAdd(&deg_dst[d.y], 1);
        atomicAdd(&deg_dst[d.z], 1); atomicAdd(&deg_dst[d.w], 1);
    } else {
        for (int i = base; i < E; ++i) {
            atomicAdd(&deg_src[src[i]], 1);
            atomicAdd(&deg_dst[dst[i]], 1);
        }
    }
}

__global__ void norm_src_kernel(const int* __restrict__ deg_src, int n_src,
                                float* __restrict__ norm_src) {
    int t = blockIdx.x * blockDim.x + threadIdx.x;
    if (t < n_src) {
        int s = deg_src[t]; if (s < 1) s = 1;
        norm_src[t] = 1.0f / (float)s;
    }
}

__global__ void fill_kernel(const int* __restrict__ src, const int* __restrict__ dst, int E,
                            const int* __restrict__ offset, int* __restrict__ cursor,
                            int* __restrict__ csr_src) {
    int t = blockIdx.x * blockDim.x + threadIdx.x;
    int base = t * 4;
    if (base + 3 < E) {
        int4 s = *(const int4*)(src + base);
        int4 d = *(const int4*)(dst + base);
        int p;
        p = offset[d.x] + atomicAdd(&cursor[d.x], 1); csr_src[p] = s.x;
        p = offset[d.y] + atomicAdd(&cursor[d.y], 1); csr_src[p] = s.y;
        p = offset[d.z] + atomicAdd(&cursor[d.z], 1); csr_src[p] = s.z;
        p = offset[d.w] + atomicAdd(&cursor[d.w], 1); csr_src[p] = s.w;
    } else {
        for (int i = base; i < E; ++i) {
            int d = dst[i];
            int p = offset[d] + atomicAdd(&cursor[d], 1);
            csr_src[p] = src[i];
        }
    }
}

__global__ void scatter_kernel(const float* __restrict__ h,
                               const int* __restrict__ src, const int* __restrict__ dst,
                               const float* __restrict__ norm_src,
                               float* __restrict__ out, int E) {
    long long t = (long long)blockIdx.x * blockDim.x + threadIdx.x;
    int e = (int)(t >> 6);
    if (e >= E) return;
    int j = (int)(t & 63);
    int s = src[e];
    float v = h[s * D + j] * norm_src[s];
    unsafeAtomicAdd(&out[dst[e] * D + j], v);
}

__global__ void scale_kernel(float* __restrict__ out, const int* __restrict__ deg_dst, int n) {
    int t = blockIdx.x * blockDim.x + threadIdx.x;
    if (t < n) {
        int dg = deg_dst[t >> 6]; if (dg < 1) dg = 1;
        out[t] *= 1.0f / (float)dg;
    }
}

extern "C" void kernel_launch(void* const* d_in, const int* in_sizes, int n_in,
                              void* d_out, int out_size, void* d_ws, size_t ws_size,
                              hipStream_t stream) {
    const float* h   = (const float*)d_in[0];
    const int*   src = (const int*)d_in[1];
    const int*   dst = (const int*)d_in[2];
    float* out = (float*)d_out;

    const int E     = in_sizes[1];
    const int n_src = in_sizes[0] / D;
    const int n_dst = out_size / D;

    // ---- Path A: atomic-free counting sort ----
    const int n_scan = 2 * NBUCK * NCHUNK;               // 1,048,576
    const int nb_scan = n_scan / SCAN_B;                 // 4096
    size_t needA = ((size_t)n_scan + nb_scan + 2 * (size_t)E
                    + 2 * (size_t)n_dst + n_src) * 4 + (size_t)E;

    if (ws_size >= needA && n_src <= NBUCK * 128 && n_dst <= NBUCK * 128) {
        int* cnt    = (int*)d_ws;                        // n_scan
        int* bsums  = cnt + n_scan;                      // nb_scan
        int* packD  = bsums + nb_scan;                   // E
        int* csr    = packD + E;                         // E
        int* deg    = csr + E;                           // n_dst
        int* offset = deg + n_dst;                       // n_dst
        float* norm_src = (float*)(offset + n_dst);      // n_src
        unsigned char* srtS = (unsigned char*)(norm_src + n_src); // E bytes

        int epc = (E + NCHUNK - 1) / NCHUNK;

        p1_count<<<NCHUNK, 256, 0, stream>>>(src, dst, E, epc, cnt);
        scan1_kernel<<<nb_scan, SCAN_B, 0, stream>>>(cnt, n_scan, cnt, bsums);
        scan2_kernel<<<1, 1024, 0, stream>>>(bsums, nb_scan);
        scan3_kernel<<<nb_scan, SCAN_B, 0, stream>>>(cnt, bsums, n_scan);
        p2_scatter<<<NCHUNK, 256, 0, stream>>>(src, dst, E, epc, cnt, packD, srtS);
        p3_place<<<NBUCK, 256, 0, stream>>>(packD, cnt, E, n_dst, csr, offset, deg);
        p3s_norm<<<NBUCK, 256, 0, stream>>>(srtS, cnt, E, n_src, norm_src);

        long long gthreads = (long long)n_dst * D;
        gather_kernel<<<(int)((gthreads + 255) / 256), 256, 0, stream>>>(
            (const float4*)h, csr, offset, deg, norm_src, (float4*)out, n_dst);
        return;
    }

    // ---- Path B: CSR via device atomics ----
    const int nbB = (n_dst + SCAN_B - 1) / SCAN_B;
    const int nbB_pad = ((nbB + 1023) / 1024) * 1024;
    const int eb4 = (E + 4 * 256 - 1) / (4 * 256);
    const int nblk = ((n_src > n_dst ? n_src : n_dst) + 255) / 256;
    size_t needB = ((size_t)n_src * 2 + (size_t)n_dst * 3 + nbB_pad) * 4 + (size_t)E * 4;

    if (ws_size >= needB) {
        int* deg_src = (int*)d_ws;
        int* deg_dst = deg_src + n_src;
        int* cursor  = deg_dst + n_dst;
        int* offset  = cursor + n_dst;
        int* bsums   = offset + n_dst;
        float* norm_src = (float*)(bsums + nbB_pad);
        int* csr_src = (int*)(norm_src + n_src);

        hipMemsetAsync(d_ws, 0, sizeof(int) * (size_t)(n_src + 2 * (size_t)n_dst), stream);
        degree_kernel<<<eb4, 256, 0, stream>>>(src, dst, E, deg_src, deg_dst);
        norm_src_kernel<<<nblk, 256, 0, stream>>>(deg_src, n_src, norm_src);
        scan1_kernel<<<nbB, SCAN_B, 0, stream>>>(deg_dst, n_dst, offset, bsums);
        scan2_kernel<<<1, 1024, 0, stream>>>(bsums, nbB);
        scan3_kernel<<<nbB, SCAN_B, 0, stream>>>(offset, bsums, n_dst);
        fill_kernel<<<eb4, 256, 0, stream>>>(src, dst, E, offset, cursor, csr_src);
        long long gthreads = (long long)n_dst * D;
        gather_kernel<<<(int)((gthreads + 255) / 256), 256, 0, stream>>>(
            (const float4*)h, csr_src, offset, deg_dst, norm_src, (float4*)out, n_dst);
        return;
    }

    // ---- Path C: minimal atomic scatter ----
    {
        int* deg_src = (int*)d_ws;
        int* deg_dst = deg_src + n_src;
        float* norm_src = (float*)(deg_dst + n_dst);
        hipMemsetAsync(d_ws, 0, sizeof(int) * (size_t)(n_src + n_dst), stream);
        hipMemsetAsync(d_out, 0, sizeof(float) * (size_t)out_size, stream);
        degree_kernel<<<eb4, 256, 0, stream>>>(src, dst, E, deg_src, deg_dst);
        norm_src_kernel<<<nblk, 256, 0, stream>>>(deg_src, n_src, norm_src);
        long long total = (long long)E * D;
        scatter_kernel<<<(int)((total + 255) / 256), 256, 0, stream>>>(h, src, dst, norm_src, out, E);
        scale_kernel<<<(out_size + 255) / 256, 256, 0, stream>>>(out, deg_dst, out_size);
    }
}

// Round 6
// 141.575 us; speedup vs baseline: 3.5662x; 1.1446x over previous
//
#include <hip/hip_runtime.h>

#define D 64
#define SCAN_B 256
#define NBUCK 1024   // coarse buckets: key >> 7
#define BSH 7
#define BMSK 127
#define NCHUNK 512   // edge chunks for count/scatter passes

// ================= Path A: atomic-free two-level counting sort =================

// P1: per (bucket, chunk) counts for dst and src, bucket-major layout.
__global__ void p1_count(const int* __restrict__ src, const int* __restrict__ dst, int E,
                         int epc, int* __restrict__ cnt) {
    __shared__ int cd[NBUCK], cs[NBUCK];
    int c = blockIdx.x;
    for (int i = threadIdx.x; i < NBUCK; i += 256) { cd[i] = 0; cs[i] = 0; }
    __syncthreads();
    int beg = c * epc, end = min(E, beg + epc);
    for (int i = beg + threadIdx.x; i < end; i += 256) {
        atomicAdd(&cd[((unsigned)dst[i]) >> BSH], 1);
        atomicAdd(&cs[((unsigned)src[i]) >> BSH], 1);
    }
    __syncthreads();
    for (int b = threadIdx.x; b < NBUCK; b += 256) {
        cnt[(size_t)b * NCHUNK + c] = cd[b];
        cnt[(size_t)(NBUCK + b) * NCHUNK + c] = cs[b];
    }
}

// scanA: one block per bucket-row: exclusive scan of its NCHUNK counts in place,
// row total -> btot[row].  256 threads x 2 consecutive entries each.
__global__ void scanA_kernel(int* __restrict__ cnt, int* __restrict__ btot) {
    __shared__ int lds[256];
    int g = blockIdx.x;
    int* e = cnt + (size_t)g * NCHUNK;
    int t = threadIdx.x;
    int a0 = e[2 * t], a1 = e[2 * t + 1];
    int p = a0 + a1;
    lds[t] = p;
    __syncthreads();
    for (int off = 1; off < 256; off <<= 1) {
        int v = (t >= off) ? lds[t - off] : 0;
        __syncthreads();
        lds[t] += v;
        __syncthreads();
    }
    int incl = lds[t];
    int excl = incl - p;
    e[2 * t] = excl;
    e[2 * t + 1] = excl + a0;
    if (t == 255) btot[g] = incl;
}

// scanB: exclusive scan of the 2*NBUCK row totals in place (1 block, 1024 thr).
__global__ void scanB_kernel(int* __restrict__ btot) {
    __shared__ int lds[1024];
    int t = threadIdx.x;
    int a0 = btot[2 * t], a1 = btot[2 * t + 1];
    int p = a0 + a1;
    lds[t] = p;
    __syncthreads();
    for (int off = 1; off < 1024; off <<= 1) {
        int v = (t >= off) ? lds[t - off] : 0;
        __syncthreads();
        lds[t] += v;
        __syncthreads();
    }
    int incl = lds[t];
    int excl = incl - p;
    btot[2 * t] = excl;
    btot[2 * t + 1] = excl + a0;
}

// P2: scatter edges into bucket-partitioned arrays via LDS cursors.
__global__ void p2_scatter(const int* __restrict__ src, const int* __restrict__ dst, int E,
                           int epc, const int* __restrict__ cnt, const int* __restrict__ btot,
                           int* __restrict__ packD, unsigned char* __restrict__ srtS) {
    __shared__ int curD[NBUCK], curS[NBUCK];
    int c = blockIdx.x;
    for (int b = threadIdx.x; b < NBUCK; b += 256) {
        curD[b] = btot[b] + cnt[(size_t)b * NCHUNK + c];
        curS[b] = btot[NBUCK + b] + cnt[(size_t)(NBUCK + b) * NCHUNK + c] - E;
    }
    __syncthreads();
    int beg = c * epc, end = min(E, beg + epc);
    for (int i = beg + threadIdx.x; i < end; i += 256) {
        int d = dst[i], s = src[i];
        int pd = atomicAdd(&curD[((unsigned)d) >> BSH], 1);
        packD[pd] = (s << BSH) | (d & BMSK);
        int ps = atomicAdd(&curS[((unsigned)s) >> BSH], 1);
        srtS[ps] = (unsigned char)(s & BMSK);
    }
}

// P3 merged: blocks [0,NBUCK) place dst CSR; blocks [NBUCK,2*NBUCK) compute
// src norms AND write feat = h * norm_src for their 128 src rows.
__global__ void p3_merged(const int* __restrict__ packD, const unsigned char* __restrict__ srtS,
                          const int* __restrict__ btot, const float4* __restrict__ h4,
                          int E, int n_dst, int n_src,
                          int* __restrict__ csr, int2* __restrict__ od_arr,
                          float4* __restrict__ feat4) {
    __shared__ int hist[128];
    __shared__ int excl[128];
    __shared__ float nrm[128];
    int blk = blockIdx.x;
    if (blk < NBUCK) {
        int b = blk;
        int beg = btot[b];
        int end = btot[b + 1];          // btot[NBUCK] == E (start of src region)
        if (threadIdx.x < 128) hist[threadIdx.x] = 0;
        __syncthreads();
        for (int i = beg + threadIdx.x; i < end; i += 256)
            atomicAdd(&hist[packD[i] & BMSK], 1);
        __syncthreads();
        if (threadIdx.x < 128) excl[threadIdx.x] = hist[threadIdx.x];
        __syncthreads();
        for (int off = 1; off < 128; off <<= 1) {
            int v = 0;
            if (threadIdx.x < 128 && threadIdx.x >= off) v = excl[threadIdx.x - off];
            __syncthreads();
            if (threadIdx.x < 128) excl[threadIdx.x] += v;
            __syncthreads();
        }
        int h = 0;
        if (threadIdx.x < 128) h = hist[threadIdx.x];
        __syncthreads();
        if (threadIdx.x < 128) {
            int ex = excl[threadIdx.x] - h;
            int dbin = b * 128 + threadIdx.x;
            if (dbin < n_dst) od_arr[dbin] = make_int2(beg + ex, h);
            hist[threadIdx.x] = ex;     // becomes cursor
        }
        __syncthreads();
        for (int i = beg + threadIdx.x; i < end; i += 256) {
            int v = packD[i];
            int pos = beg + atomicAdd(&hist[v & BMSK], 1);
            csr[pos] = v >> BSH;
        }
    } else {
        int row = blk;                  // NBUCK..2*NBUCK-1
        int b = blk - NBUCK;
        int beg = btot[row] - E;
        int end = ((row + 1 < 2 * NBUCK) ? btot[row + 1] : 2 * E) - E;
        if (threadIdx.x < 128) hist[threadIdx.x] = 0;
        __syncthreads();
        for (int i = beg + threadIdx.x; i < end; i += 256)
            atomicAdd(&hist[srtS[i]], 1);
        __syncthreads();
        if (threadIdx.x < 128) {
            int h = hist[threadIdx.x]; if (h < 1) h = 1;
            nrm[threadIdx.x] = 1.0f / (float)h;
        }
        __syncthreads();
        for (int i = threadIdx.x; i < 128 * 16; i += 256) {
            int r = i >> 4, l = i & 15;
            int gsrc = b * 128 + r;
            if (gsrc < n_src) {
                float4 v = h4[(size_t)gsrc * 16 + l];
                float nm = nrm[r];
                v.x *= nm; v.y *= nm; v.z *= nm; v.w *= nm;
                feat4[(size_t)gsrc * 16 + l] = v;
            }
        }
    }
}

// gather: one wave per dst row; 8 edge-groups x 8 lanes x 2 float4.
__global__ void gather_feat(const float4* __restrict__ feat4, const int* __restrict__ csr,
                            const int2* __restrict__ od_arr,
                            float4* __restrict__ out4, int n_dst) {
    int gid = blockIdx.x * blockDim.x + threadIdx.x;
    int row = gid >> 6;
    if (row >= n_dst) return;
    int lane = threadIdx.x & 63;
    int g = lane >> 3;       // edge group 0..7
    int l8 = lane & 7;       // float4 slot pair base
    int2 od = od_arr[row];
    int beg = od.x, dg = od.y;
    int end = beg + dg;
    float4 a0 = {0.f, 0.f, 0.f, 0.f};
    float4 a1 = {0.f, 0.f, 0.f, 0.f};
    for (int k = beg + g; k < end; k += 8) {
        int s = csr[k];
        float4 v0 = feat4[(size_t)s * 16 + l8];
        float4 v1 = feat4[(size_t)s * 16 + 8 + l8];
        a0.x += v0.x; a0.y += v0.y; a0.z += v0.z; a0.w += v0.w;
        a1.x += v1.x; a1.y += v1.y; a1.z += v1.z; a1.w += v1.w;
    }
    #pragma unroll
    for (int m = 8; m < 64; m <<= 1) {
        a0.x += __shfl_xor(a0.x, m); a0.y += __shfl_xor(a0.y, m);
        a0.z += __shfl_xor(a0.z, m); a0.w += __shfl_xor(a0.w, m);
        a1.x += __shfl_xor(a1.x, m); a1.y += __shfl_xor(a1.y, m);
        a1.z += __shfl_xor(a1.z, m); a1.w += __shfl_xor(a1.w, m);
    }
    if (g == 0) {
        float nd = 1.0f / (float)(dg < 1 ? 1 : dg);
        float4 r0, r1;
        r0.x = a0.x * nd; r0.y = a0.y * nd; r0.z = a0.z * nd; r0.w = a0.w * nd;
        r1.x = a1.x * nd; r1.y = a1.y * nd; r1.z = a1.z * nd; r1.w = a1.w * nd;
        out4[(size_t)row * 16 + l8] = r0;
        out4[(size_t)row * 16 + 8 + l8] = r1;
    }
}

// ====================== legacy kernels (paths A2/B/C) ======================
__global__ void scan1_kernel(const int* __restrict__ deg, int n,
                             int* __restrict__ out, int* __restrict__ bsums) {
    __shared__ int tmp[SCAN_B];
    int t = blockIdx.x * SCAN_B + threadIdx.x;
    int v = (t < n) ? deg[t] : 0;
    tmp[threadIdx.x] = v;
    __syncthreads();
    for (int off = 1; off < SCAN_B; off <<= 1) {
        int add = (threadIdx.x >= off) ? tmp[threadIdx.x - off] : 0;
        __syncthreads();
        tmp[threadIdx.x] += add;
        __syncthreads();
    }
    if (t < n) out[t] = tmp[threadIdx.x] - v;
    if (threadIdx.x == SCAN_B - 1) bsums[blockIdx.x] = tmp[threadIdx.x];
}

__global__ void scan2_kernel(int* __restrict__ bsums, int nb) {
    __shared__ int tmp[1024];
    __shared__ int carry_s;
    if (threadIdx.x == 0) carry_s = 0;
    __syncthreads();
    for (int base = 0; base < nb; base += 1024) {
        int i = base + threadIdx.x;
        int v = (i < nb) ? bsums[i] : 0;
        tmp[threadIdx.x] = v;
        __syncthreads();
        for (int off = 1; off < 1024; off <<= 1) {
            int add = (threadIdx.x >= off) ? tmp[threadIdx.x - off] : 0;
            __syncthreads();
            tmp[threadIdx.x] += add;
            __syncthreads();
        }
        int incl = tmp[threadIdx.x];
        int carry = carry_s;
        if (i < nb) bsums[i] = incl - v + carry;
        __syncthreads();
        if (threadIdx.x == 0) carry_s = carry + tmp[1023];
        __syncthreads();
    }
}

__global__ void scan3_kernel(int* __restrict__ out, const int* __restrict__ bsums, int n) {
    int t = blockIdx.x * SCAN_B + threadIdx.x;
    if (t < n) out[t] += bsums[blockIdx.x];
}

__global__ void p3_place(const int* __restrict__ packD, const int* __restrict__ btot,
                         int E, int n_dst,
                         int* __restrict__ csr, int* __restrict__ offset,
                         int* __restrict__ deg) {
    __shared__ int hist[128];
    __shared__ int excl[128];
    int b = blockIdx.x;
    int beg = btot[b];
    int end = btot[b + 1];
    if (threadIdx.x < 128) hist[threadIdx.x] = 0;
    __syncthreads();
    for (int i = beg + threadIdx.x; i < end; i += 256)
        atomicAdd(&hist[packD[i] & BMSK], 1);
    __syncthreads();
    if (threadIdx.x < 128) excl[threadIdx.x] = hist[threadIdx.x];
    __syncthreads();
    for (int off = 1; off < 128; off <<= 1) {
        int v = 0;
        if (threadIdx.x < 128 && threadIdx.x >= off) v = excl[threadIdx.x - off];
        __syncthreads();
        if (threadIdx.x < 128) excl[threadIdx.x] += v;
        __syncthreads();
    }
    int h = 0;
    if (threadIdx.x < 128) h = hist[threadIdx.x];
    __syncthreads();
    if (threadIdx.x < 128) {
        int ex = excl[threadIdx.x] - h;
        int dbin = b * 128 + threadIdx.x;
        if (dbin < n_dst) { deg[dbin] = h; offset[dbin] = beg + ex; }
        hist[threadIdx.x] = ex;
    }
    __syncthreads();
    for (int i = beg + threadIdx.x; i < end; i += 256) {
        int v = packD[i];
        int pos = beg + atomicAdd(&hist[v & BMSK], 1);
        csr[pos] = v >> BSH;
    }
}

__global__ void p3s_norm(const unsigned char* __restrict__ srtS, const int* __restrict__ btot,
                         int E, int n_src, float* __restrict__ norm_src) {
    __shared__ int hist[128];
    int b = blockIdx.x;
    int row = NBUCK + b;
    int beg = btot[row] - E;
    int end = ((row + 1 < 2 * NBUCK) ? btot[row + 1] : 2 * E) - E;
    if (threadIdx.x < 128) hist[threadIdx.x] = 0;
    __syncthreads();
    for (int i = beg + threadIdx.x; i < end; i += 256)
        atomicAdd(&hist[srtS[i]], 1);
    __syncthreads();
    if (threadIdx.x < 128) {
        int sbin = b * 128 + threadIdx.x;
        if (sbin < n_src) {
            int h = hist[threadIdx.x]; if (h < 1) h = 1;
            norm_src[sbin] = 1.0f / (float)h;
        }
    }
}

__global__ void gather_kernel(const float4* __restrict__ h4, const int* __restrict__ csr_src,
                              const int* __restrict__ offset, const int* __restrict__ deg_dst,
                              const float* __restrict__ norm_src,
                              float4* __restrict__ out4, int n_dst) {
    int gid = blockIdx.x * blockDim.x + threadIdx.x;
    int row = gid >> 6;
    if (row >= n_dst) return;
    int lane = threadIdx.x & 63;
    int g = lane >> 4;
    int l16 = lane & 15;
    int beg = offset[row];
    int deg = deg_dst[row];
    int end = beg + deg;
    float ax = 0.f, ay = 0.f, az = 0.f, aw = 0.f;
    for (int k = beg + g; k < end; k += 4) {
        int s = csr_src[k];
        float ns = norm_src[s];
        float4 v = h4[s * 16 + l16];
        ax = fmaf(v.x, ns, ax);
        ay = fmaf(v.y, ns, ay);
        az = fmaf(v.z, ns, az);
        aw = fmaf(v.w, ns, aw);
    }
    ax += __shfl_xor(ax, 16); ay += __shfl_xor(ay, 16);
    az += __shfl_xor(az, 16); aw += __shfl_xor(aw, 16);
    ax += __shfl_xor(ax, 32); ay += __shfl_xor(ay, 32);
    az += __shfl_xor(az, 32); aw += __shfl_xor(aw, 32);
    if (g == 0) {
        int dg = deg < 1 ? 1 : deg;
        float nd = 1.0f / (float)dg;
        float4 r;
        r.x = ax * nd; r.y = ay * nd; r.z = az * nd; r.w = aw * nd;
        out4[row * 16 + l16] = r;
    }
}

__global__ void degree_kernel(const int* __restrict__ src, const int* __restrict__ dst,
                              int E, int* __restrict__ deg_src, int* __restrict__ deg_dst) {
    int t = blockIdx.x * blockDim.x + threadIdx.x;
    int base = t * 4;
    if (base + 3 < E) {
        int4 s = *(const int4*)(src + base);
        int4 d = *(const int4*)(dst + base);
        atomicAdd(&deg_src[s.x], 1); atomicAdd(&deg_src[s.y], 1);
        atomicAdd(&deg_src[s.z], 1); atomicAdd(&deg_src[s.w], 1);
        atomicAdd(&deg_dst[d.x], 1); atomicAdd(&deg_dst[d.y], 1);
        atomicAdd(&deg_dst[d.z], 1); atomicAdd(&deg_dst[d.w], 1);
    } else {
        for (int i = base; i < E; ++i) {
            atomicAdd(&deg_src[src[i]], 1);
            atomicAdd(&deg_dst[dst[i]], 1);
        }
    }
}

__global__ void norm_src_kernel(const int* __restrict__ deg_src, int n_src,
                                float* __restrict__ norm_src) {
    int t = blockIdx.x * blockDim.x + threadIdx.x;
    if (t < n_src) {
        int s = deg_src[t]; if (s < 1) s = 1;
        norm_src[t] = 1.0f / (float)s;
    }
}

__global__ void fill_kernel(const int* __restrict__ src, const int* __restrict__ dst, int E,
                            const int* __restrict__ offset, int* __restrict__ cursor,
                            int* __restrict__ csr_src) {
    int t = blockIdx.x * blockDim.x + threadIdx.x;
    int base = t * 4;
    if (base + 3 < E) {
        int4 s = *(const int4*)(src + base);
        int4 d = *(const int4*)(dst + base);
        int p;
        p = offset[d.x] + atomicAdd(&cursor[d.x], 1); csr_src[p] = s.x;
        p = offset[d.y] + atomicAdd(&cursor[d.y], 1); csr_src[p] = s.y;
        p = offset[d.z] + atomicAdd(&cursor[d.z], 1); csr_src[p] = s.z;
        p = offset[d.w] + atomicAdd(&cursor[d.w], 1); csr_src[p] = s.w;
    } else {
        for (int i = base; i < E; ++i) {
            int d = dst[i];
            int p = offset[d] + atomicAdd(&cursor[d], 1);
            csr_src[p] = src[i];
        }
    }
}

__global__ void scatter_kernel(const float* __restrict__ h,
                               const int* __restrict__ src, const int* __restrict__ dst,
                               const float* __restrict__ norm_src,
                               float* __restrict__ out, int E) {
    long long t = (long long)blockIdx.x * blockDim.x + threadIdx.x;
    int e = (int)(t >> 6);
    if (e >= E) return;
    int j = (int)(t & 63);
    int s = src[e];
    float v = h[s * D + j] * norm_src[s];
    unsafeAtomicAdd(&out[dst[e] * D + j], v);
}

__global__ void scale_kernel(float* __restrict__ out, const int* __restrict__ deg_dst, int n) {
    int t = blockIdx.x * blockDim.x + threadIdx.x;
    if (t < n) {
        int dg = deg_dst[t >> 6]; if (dg < 1) dg = 1;
        out[t] *= 1.0f / (float)dg;
    }
}

extern "C" void kernel_launch(void* const* d_in, const int* in_sizes, int n_in,
                              void* d_out, int out_size, void* d_ws, size_t ws_size,
                              hipStream_t stream) {
    const float* h   = (const float*)d_in[0];
    const int*   src = (const int*)d_in[1];
    const int*   dst = (const int*)d_in[2];
    float* out = (float*)d_out;

    const int E     = in_sizes[1];
    const int n_src = in_sizes[0] / D;
    const int n_dst = out_size / D;
    const int n_scan = 2 * NBUCK * NCHUNK;
    const int epc = (E + NCHUNK - 1) / NCHUNK;

    // ---- Path A: sort + feat-precompute + 8-group gather ----
    size_t needA = ((size_t)n_scan + 2 * NBUCK + 2 * (size_t)E
                    + 2 * (size_t)n_dst + 64 * (size_t)n_src) * 4 + (size_t)E;

    if (ws_size >= needA && n_src <= NBUCK * 128 && n_dst <= NBUCK * 128 &&
        epc <= 1 << 20) {
        int* cnt    = (int*)d_ws;                        // n_scan
        int* btot   = cnt + n_scan;                      // 2*NBUCK
        int* packD  = btot + 2 * NBUCK;                  // E
        int* csr    = packD + E;                         // E
        int2* od    = (int2*)(csr + E);                  // n_dst int2
        float4* feat4 = (float4*)(od + n_dst);           // n_src*16 float4
        unsigned char* srtS = (unsigned char*)(feat4 + (size_t)n_src * 16); // E bytes

        p1_count<<<NCHUNK, 256, 0, stream>>>(src, dst, E, epc, cnt);
        scanA_kernel<<<2 * NBUCK, 256, 0, stream>>>(cnt, btot);
        scanB_kernel<<<1, 1024, 0, stream>>>(btot);
        p2_scatter<<<NCHUNK, 256, 0, stream>>>(src, dst, E, epc, cnt, btot, packD, srtS);
        p3_merged<<<2 * NBUCK, 256, 0, stream>>>(packD, srtS, btot, (const float4*)h,
                                                 E, n_dst, n_src, csr, od, feat4);
        long long gthreads = (long long)n_dst * D;
        gather_feat<<<(int)((gthreads + 255) / 256), 256, 0, stream>>>(
            feat4, csr, od, (float4*)out, n_dst);
        return;
    }

    // ---- Path A2: R5 pipeline (no feat buffer needed) ----
    size_t needA2 = ((size_t)n_scan + 2 * NBUCK + 2 * (size_t)E
                     + 2 * (size_t)n_dst + n_src) * 4 + (size_t)E;
    if (ws_size >= needA2 && n_src <= NBUCK * 128 && n_dst <= NBUCK * 128) {
        int* cnt    = (int*)d_ws;
        int* btot   = cnt + n_scan;
        int* packD  = btot + 2 * NBUCK;
        int* csr    = packD + E;
        int* deg    = csr + E;
        int* offset = deg + n_dst;
        float* norm_src = (float*)(offset + n_dst);
        unsigned char* srtS = (unsigned char*)(norm_src + n_src);

        p1_count<<<NCHUNK, 256, 0, stream>>>(src, dst, E, epc, cnt);
        scanA_kernel<<<2 * NBUCK, 256, 0, stream>>>(cnt, btot);
        scanB_kernel<<<1, 1024, 0, stream>>>(btot);
        p2_scatter<<<NCHUNK, 256, 0, stream>>>(src, dst, E, epc, cnt, btot, packD, srtS);
        p3_place<<<NBUCK, 256, 0, stream>>>(packD, btot, E, n_dst, csr, offset, deg);
        p3s_norm<<<NBUCK, 256, 0, stream>>>(srtS, btot, E, n_src, norm_src);
        long long gthreads = (long long)n_dst * D;
        gather_kernel<<<(int)((gthreads + 255) / 256), 256, 0, stream>>>(
            (const float4*)h, csr, offset, deg, norm_src, (float4*)out, n_dst);
        return;
    }

    // ---- Path B: CSR via device atomics ----
    const int nbB = (n_dst + SCAN_B - 1) / SCAN_B;
    const int nbB_pad = ((nbB + 1023) / 1024) * 1024;
    const int eb4 = (E + 4 * 256 - 1) / (4 * 256);
    const int nblk = ((n_src > n_dst ? n_src : n_dst) + 255) / 256;
    size_t needB = ((size_t)n_src * 2 + (size_t)n_dst * 3 + nbB_pad) * 4 + (size_t)E * 4;

    if (ws_size >= needB) {
        int* deg_src = (int*)d_ws;
        int* deg_dst = deg_src + n_src;
        int* cursor  = deg_dst + n_dst;
        int* offset  = cursor + n_dst;
        int* bsums   = offset + n_dst;
        float* norm_src = (float*)(bsums + nbB_pad);
        int* csr_src = (int*)(norm_src + n_src);

        hipMemsetAsync(d_ws, 0, sizeof(int) * (size_t)(n_src + 2 * (size_t)n_dst), stream);
        degree_kernel<<<eb4, 256, 0, stream>>>(src, dst, E, deg_src, deg_dst);
        norm_src_kernel<<<nblk, 256, 0, stream>>>(deg_src, n_src, norm_src);
        scan1_kernel<<<nbB, SCAN_B, 0, stream>>>(deg_dst, n_dst, offset, bsums);
        scan2_kernel<<<1, 1024, 0, stream>>>(bsums, nbB);
        scan3_kernel<<<nbB, SCAN_B, 0, stream>>>(offset, bsums, n_dst);
        fill_kernel<<<eb4, 256, 0, stream>>>(src, dst, E, offset, cursor, csr_src);
        long long gthreads = (long long)n_dst * D;
        gather_kernel<<<(int)((gthreads + 255) / 256), 256, 0, stream>>>(
            (const float4*)h, csr_src, offset, deg_dst, norm_src, (float4*)out, n_dst);
        return;
    }

    // ---- Path C: minimal atomic scatter ----
    {
        int* deg_src = (int*)d_ws;
        int* deg_dst = deg_src + n_src;
        float* norm_src = (float*)(deg_dst + n_dst);
        hipMemsetAsync(d_ws, 0, sizeof(int) * (size_t)(n_src + n_dst), stream);
        hipMemsetAsync(d_out, 0, sizeof(float) * (size_t)out_size, stream);
        degree_kernel<<<eb4, 256, 0, stream>>>(src, dst, E, deg_src, deg_dst);
        norm_src_kernel<<<nblk, 256, 0, stream>>>(deg_src, n_src, norm_src);
        long long total = (long long)E * D;
        scatter_kernel<<<(int)((total + 255) / 256), 256, 0, stream>>>(h, src, dst, norm_src, out, E);
        scale_kernel<<<(out_size + 255) / 256, 256, 0, stream>>>(out, deg_dst, out_size);
    }
}

// Round 7
// 128.890 us; speedup vs baseline: 3.9172x; 1.0984x over previous
//
#include <hip/hip_runtime.h>

#define D 64
#define SCAN_B 256
#define NBUCK 1024   // coarse buckets: key >> 7
#define BSH 7
#define BMSK 127
#define NCHUNK 512   // edge chunks for count/scatter passes

typedef __attribute__((ext_vector_type(8))) unsigned short ushort8_t;

__device__ __forceinline__ unsigned short f2bf(float f) {
    unsigned u = __float_as_uint(f);
    unsigned r = (u + 0x7FFFu + ((u >> 16) & 1u)) >> 16;   // RNE
    return (unsigned short)r;
}

// ================= Path A: atomic-free two-level counting sort =================

// P1: per (bucket, chunk) counts for dst and src, bucket-major layout.
__global__ void p1_count(const int* __restrict__ src, const int* __restrict__ dst, int E,
                         int epc, int* __restrict__ cnt) {
    __shared__ int cd[NBUCK], cs[NBUCK];
    int c = blockIdx.x;
    for (int i = threadIdx.x; i < NBUCK; i += 256) { cd[i] = 0; cs[i] = 0; }
    __syncthreads();
    int beg = c * epc, end = min(E, beg + epc);
    for (int i = beg + threadIdx.x; i < end; i += 256) {
        atomicAdd(&cd[((unsigned)dst[i]) >> BSH], 1);
        atomicAdd(&cs[((unsigned)src[i]) >> BSH], 1);
    }
    __syncthreads();
    for (int b = threadIdx.x; b < NBUCK; b += 256) {
        cnt[(size_t)b * NCHUNK + c] = cd[b];
        cnt[(size_t)(NBUCK + b) * NCHUNK + c] = cs[b];
    }
}

// scanA: one block per bucket-row: exclusive scan of its NCHUNK counts in place.
__global__ void scanA_kernel(int* __restrict__ cnt, int* __restrict__ btot) {
    __shared__ int lds[256];
    int g = blockIdx.x;
    int* e = cnt + (size_t)g * NCHUNK;
    int t = threadIdx.x;
    int a0 = e[2 * t], a1 = e[2 * t + 1];
    int p = a0 + a1;
    lds[t] = p;
    __syncthreads();
    for (int off = 1; off < 256; off <<= 1) {
        int v = (t >= off) ? lds[t - off] : 0;
        __syncthreads();
        lds[t] += v;
        __syncthreads();
    }
    int incl = lds[t];
    int excl = incl - p;
    e[2 * t] = excl;
    e[2 * t + 1] = excl + a0;
    if (t == 255) btot[g] = incl;
}

// scanB: exclusive scan of the 2*NBUCK row totals in place (1 block, 1024 thr).
__global__ void scanB_kernel(int* __restrict__ btot) {
    __shared__ int lds[1024];
    int t = threadIdx.x;
    int a0 = btot[2 * t], a1 = btot[2 * t + 1];
    int p = a0 + a1;
    lds[t] = p;
    __syncthreads();
    for (int off = 1; off < 1024; off <<= 1) {
        int v = (t >= off) ? lds[t - off] : 0;
        __syncthreads();
        lds[t] += v;
        __syncthreads();
    }
    int incl = lds[t];
    int excl = incl - p;
    btot[2 * t] = excl;
    btot[2 * t + 1] = excl + a0;
}

// P2: scatter edges into bucket-partitioned arrays via LDS cursors.
__global__ void p2_scatter(const int* __restrict__ src, const int* __restrict__ dst, int E,
                           int epc, const int* __restrict__ cnt, const int* __restrict__ btot,
                           int* __restrict__ packD, unsigned char* __restrict__ srtS) {
    __shared__ int curD[NBUCK], curS[NBUCK];
    int c = blockIdx.x;
    for (int b = threadIdx.x; b < NBUCK; b += 256) {
        curD[b] = btot[b] + cnt[(size_t)b * NCHUNK + c];
        curS[b] = btot[NBUCK + b] + cnt[(size_t)(NBUCK + b) * NCHUNK + c] - E;
    }
    __syncthreads();
    int beg = c * epc, end = min(E, beg + epc);
    for (int i = beg + threadIdx.x; i < end; i += 256) {
        int d = dst[i], s = src[i];
        int pd = atomicAdd(&curD[((unsigned)d) >> BSH], 1);
        packD[pd] = (s << BSH) | (d & BMSK);
        int ps = atomicAdd(&curS[((unsigned)s) >> BSH], 1);
        srtS[ps] = (unsigned char)(s & BMSK);
    }
}

// P3 merged: blocks [0,NBUCK) place dst CSR; blocks [NBUCK,2*NBUCK) compute
// src norms AND write feat(bf16) = h * norm_src for their 128 src rows.
__global__ void p3_merged(const int* __restrict__ packD, const unsigned char* __restrict__ srtS,
                          const int* __restrict__ btot, const float4* __restrict__ h4,
                          int E, int n_dst, int n_src,
                          int* __restrict__ csr, int2* __restrict__ od_arr,
                          unsigned short* __restrict__ featb) {
    __shared__ int hist[128];
    __shared__ int excl[128];
    __shared__ float nrm[128];
    int blk = blockIdx.x;
    if (blk < NBUCK) {
        int b = blk;
        int beg = btot[b];
        int end = btot[b + 1];          // btot[NBUCK] == E
        if (threadIdx.x < 128) hist[threadIdx.x] = 0;
        __syncthreads();
        for (int i = beg + threadIdx.x; i < end; i += 256)
            atomicAdd(&hist[packD[i] & BMSK], 1);
        __syncthreads();
        if (threadIdx.x < 128) excl[threadIdx.x] = hist[threadIdx.x];
        __syncthreads();
        for (int off = 1; off < 128; off <<= 1) {
            int v = 0;
            if (threadIdx.x < 128 && threadIdx.x >= off) v = excl[threadIdx.x - off];
            __syncthreads();
            if (threadIdx.x < 128) excl[threadIdx.x] += v;
            __syncthreads();
        }
        int h = 0;
        if (threadIdx.x < 128) h = hist[threadIdx.x];
        __syncthreads();
        if (threadIdx.x < 128) {
            int ex = excl[threadIdx.x] - h;
            int dbin = b * 128 + threadIdx.x;
            if (dbin < n_dst) od_arr[dbin] = make_int2(beg + ex, h);
            hist[threadIdx.x] = ex;     // becomes cursor
        }
        __syncthreads();
        for (int i = beg + threadIdx.x; i < end; i += 256) {
            int v = packD[i];
            int pos = beg + atomicAdd(&hist[v & BMSK], 1);
            csr[pos] = v >> BSH;
        }
    } else {
        int row = blk;                  // NBUCK..2*NBUCK-1
        int b = blk - NBUCK;
        int beg = btot[row] - E;
        int end = ((row + 1 < 2 * NBUCK) ? btot[row + 1] : 2 * E) - E;
        if (threadIdx.x < 128) hist[threadIdx.x] = 0;
        __syncthreads();
        for (int i = beg + threadIdx.x; i < end; i += 256)
            atomicAdd(&hist[srtS[i]], 1);
        __syncthreads();
        if (threadIdx.x < 128) {
            int h = hist[threadIdx.x]; if (h < 1) h = 1;
            nrm[threadIdx.x] = 1.0f / (float)h;
        }
        __syncthreads();
        for (int i = threadIdx.x; i < 128 * 8; i += 256) {
            int r = i >> 3, l8 = i & 7;
            int gsrc = b * 128 + r;
            if (gsrc < n_src) {
                float nm = nrm[r];
                float4 v0 = h4[(size_t)gsrc * 16 + l8 * 2];
                float4 v1 = h4[(size_t)gsrc * 16 + l8 * 2 + 1];
                ushort8_t o;
                o[0] = f2bf(v0.x * nm); o[1] = f2bf(v0.y * nm);
                o[2] = f2bf(v0.z * nm); o[3] = f2bf(v0.w * nm);
                o[4] = f2bf(v1.x * nm); o[5] = f2bf(v1.y * nm);
                o[6] = f2bf(v1.z * nm); o[7] = f2bf(v1.w * nm);
                *(ushort8_t*)(featb + (size_t)gsrc * 64 + l8 * 8) = o;
            }
        }
    }
}

// gather: one wave per dst row; 8 edge-groups x 8 lanes x ushort8 (bf16 feat),
// unrolled 2x -> 16 edges in flight per wave.
__global__ void gather_feat(const unsigned short* __restrict__ featb,
                            const int* __restrict__ csr,
                            const int2* __restrict__ od_arr,
                            float4* __restrict__ out4, int n_dst) {
    int gid = blockIdx.x * blockDim.x + threadIdx.x;
    int row = gid >> 6;
    if (row >= n_dst) return;
    int lane = threadIdx.x & 63;
    int g = lane >> 3;       // edge group 0..7
    int l8 = lane & 7;       // ushort8 slot within 64-elem row
    int2 od = od_arr[row];
    int beg = od.x, dg = od.y;
    int end = beg + dg;
    float a[8] = {0.f, 0.f, 0.f, 0.f, 0.f, 0.f, 0.f, 0.f};
    for (int k = beg + g; k < end; k += 16) {
        int s0 = csr[k];
        ushort8_t v0 = *(const ushort8_t*)(featb + (size_t)s0 * 64 + l8 * 8);
        int k2 = k + 8;
        if (k2 < end) {
            int s1 = csr[k2];
            ushort8_t v1 = *(const ushort8_t*)(featb + (size_t)s1 * 64 + l8 * 8);
            #pragma unroll
            for (int j = 0; j < 8; ++j)
                a[j] += __uint_as_float(((unsigned)v0[j]) << 16)
                      + __uint_as_float(((unsigned)v1[j]) << 16);
        } else {
            #pragma unroll
            for (int j = 0; j < 8; ++j)
                a[j] += __uint_as_float(((unsigned)v0[j]) << 16);
        }
    }
    #pragma unroll
    for (int m = 8; m < 64; m <<= 1) {
        #pragma unroll
        for (int j = 0; j < 8; ++j) a[j] += __shfl_xor(a[j], m);
    }
    if (g == 0) {
        float nd = 1.0f / (float)(dg < 1 ? 1 : dg);
        float4 r0, r1;
        r0.x = a[0] * nd; r0.y = a[1] * nd; r0.z = a[2] * nd; r0.w = a[3] * nd;
        r1.x = a[4] * nd; r1.y = a[5] * nd; r1.z = a[6] * nd; r1.w = a[7] * nd;
        out4[(size_t)row * 16 + l8 * 2]     = r0;
        out4[(size_t)row * 16 + l8 * 2 + 1] = r1;
    }
}

// ====================== legacy kernels (paths A2/B/C) ======================
__global__ void scan1_kernel(const int* __restrict__ deg, int n,
                             int* __restrict__ out, int* __restrict__ bsums) {
    __shared__ int tmp[SCAN_B];
    int t = blockIdx.x * SCAN_B + threadIdx.x;
    int v = (t < n) ? deg[t] : 0;
    tmp[threadIdx.x] = v;
    __syncthreads();
    for (int off = 1; off < SCAN_B; off <<= 1) {
        int add = (threadIdx.x >= off) ? tmp[threadIdx.x - off] : 0;
        __syncthreads();
        tmp[threadIdx.x] += add;
        __syncthreads();
    }
    if (t < n) out[t] = tmp[threadIdx.x] - v;
    if (threadIdx.x == SCAN_B - 1) bsums[blockIdx.x] = tmp[threadIdx.x];
}

__global__ void scan2_kernel(int* __restrict__ bsums, int nb) {
    __shared__ int tmp[1024];
    __shared__ int carry_s;
    if (threadIdx.x == 0) carry_s = 0;
    __syncthreads();
    for (int base = 0; base < nb; base += 1024) {
        int i = base + threadIdx.x;
        int v = (i < nb) ? bsums[i] : 0;
        tmp[threadIdx.x] = v;
        __syncthreads();
        for (int off = 1; off < 1024; off <<= 1) {
            int add = (threadIdx.x >= off) ? tmp[threadIdx.x - off] : 0;
            __syncthreads();
            tmp[threadIdx.x] += add;
            __syncthreads();
        }
        int incl = tmp[threadIdx.x];
        int carry = carry_s;
        if (i < nb) bsums[i] = incl - v + carry;
        __syncthreads();
        if (threadIdx.x == 0) carry_s = carry + tmp[1023];
        __syncthreads();
    }
}

__global__ void scan3_kernel(int* __restrict__ out, const int* __restrict__ bsums, int n) {
    int t = blockIdx.x * SCAN_B + threadIdx.x;
    if (t < n) out[t] += bsums[blockIdx.x];
}

__global__ void p3_place(const int* __restrict__ packD, const int* __restrict__ btot,
                         int E, int n_dst,
                         int* __restrict__ csr, int* __restrict__ offset,
                         int* __restrict__ deg) {
    __shared__ int hist[128];
    __shared__ int excl[128];
    int b = blockIdx.x;
    int beg = btot[b];
    int end = btot[b + 1];
    if (threadIdx.x < 128) hist[threadIdx.x] = 0;
    __syncthreads();
    for (int i = beg + threadIdx.x; i < end; i += 256)
        atomicAdd(&hist[packD[i] & BMSK], 1);
    __syncthreads();
    if (threadIdx.x < 128) excl[threadIdx.x] = hist[threadIdx.x];
    __syncthreads();
    for (int off = 1; off < 128; off <<= 1) {
        int v = 0;
        if (threadIdx.x < 128 && threadIdx.x >= off) v = excl[threadIdx.x - off];
        __syncthreads();
        if (threadIdx.x < 128) excl[threadIdx.x] += v;
        __syncthreads();
    }
    int h = 0;
    if (threadIdx.x < 128) h = hist[threadIdx.x];
    __syncthreads();
    if (threadIdx.x < 128) {
        int ex = excl[threadIdx.x] - h;
        int dbin = b * 128 + threadIdx.x;
        if (dbin < n_dst) { deg[dbin] = h; offset[dbin] = beg + ex; }
        hist[threadIdx.x] = ex;
    }
    __syncthreads();
    for (int i = beg + threadIdx.x; i < end; i += 256) {
        int v = packD[i];
        int pos = beg + atomicAdd(&hist[v & BMSK], 1);
        csr[pos] = v >> BSH;
    }
}

__global__ void p3s_norm(const unsigned char* __restrict__ srtS, const int* __restrict__ btot,
                         int E, int n_src, float* __restrict__ norm_src) {
    __shared__ int hist[128];
    int b = blockIdx.x;
    int row = NBUCK + b;
    int beg = btot[row] - E;
    int end = ((row + 1 < 2 * NBUCK) ? btot[row + 1] : 2 * E) - E;
    if (threadIdx.x < 128) hist[threadIdx.x] = 0;
    __syncthreads();
    for (int i = beg + threadIdx.x; i < end; i += 256)
        atomicAdd(&hist[srtS[i]], 1);
    __syncthreads();
    if (threadIdx.x < 128) {
        int sbin = b * 128 + threadIdx.x;
        if (sbin < n_src) {
            int h = hist[threadIdx.x]; if (h < 1) h = 1;
            norm_src[sbin] = 1.0f / (float)h;
        }
    }
}

__global__ void gather_kernel(const float4* __restrict__ h4, const int* __restrict__ csr_src,
                              const int* __restrict__ offset, const int* __restrict__ deg_dst,
                              const float* __restrict__ norm_src,
                              float4* __restrict__ out4, int n_dst) {
    int gid = blockIdx.x * blockDim.x + threadIdx.x;
    int row = gid >> 6;
    if (row >= n_dst) return;
    int lane = threadIdx.x & 63;
    int g = lane >> 4;
    int l16 = lane & 15;
    int beg = offset[row];
    int deg = deg_dst[row];
    int end = beg + deg;
    float ax = 0.f, ay = 0.f, az = 0.f, aw = 0.f;
    for (int k = beg + g; k < end; k += 4) {
        int s = csr_src[k];
        float ns = norm_src[s];
        float4 v = h4[s * 16 + l16];
        ax = fmaf(v.x, ns, ax);
        ay = fmaf(v.y, ns, ay);
        az = fmaf(v.z, ns, az);
        aw = fmaf(v.w, ns, aw);
    }
    ax += __shfl_xor(ax, 16); ay += __shfl_xor(ay, 16);
    az += __shfl_xor(az, 16); aw += __shfl_xor(aw, 16);
    ax += __shfl_xor(ax, 32); ay += __shfl_xor(ay, 32);
    az += __shfl_xor(az, 32); aw += __shfl_xor(aw, 32);
    if (g == 0) {
        int dg = deg < 1 ? 1 : deg;
        float nd = 1.0f / (float)dg;
        float4 r;
        r.x = ax * nd; r.y = ay * nd; r.z = az * nd; r.w = aw * nd;
        out4[row * 16 + l16] = r;
    }
}

__global__ void degree_kernel(const int* __restrict__ src, const int* __restrict__ dst,
                              int E, int* __restrict__ deg_src, int* __restrict__ deg_dst) {
    int t = blockIdx.x * blockDim.x + threadIdx.x;
    int base = t * 4;
    if (base + 3 < E) {
        int4 s = *(const int4*)(src + base);
        int4 d = *(const int4*)(dst + base);
        atomicAdd(&deg_src[s.x], 1); atomicAdd(&deg_src[s.y], 1);
        atomicAdd(&deg_src[s.z], 1); atomicAdd(&deg_src[s.w], 1);
        atomicAdd(&deg_dst[d.x], 1); atomicAdd(&deg_dst[d.y], 1);
        atomicAdd(&deg_dst[d.z], 1); atomicAdd(&deg_dst[d.w], 1);
    } else {
        for (int i = base; i < E; ++i) {
            atomicAdd(&deg_src[src[i]], 1);
            atomicAdd(&deg_dst[dst[i]], 1);
        }
    }
}

__global__ void norm_src_kernel(const int* __restrict__ deg_src, int n_src,
                                float* __restrict__ norm_src) {
    int t = blockIdx.x * blockDim.x + threadIdx.x;
    if (t < n_src) {
        int s = deg_src[t]; if (s < 1) s = 1;
        norm_src[t] = 1.0f / (float)s;
    }
}

__global__ void fill_kernel(const int* __restrict__ src, const int* __restrict__ dst, int E,
                            const int* __restrict__ offset, int* __restrict__ cursor,
                            int* __restrict__ csr_src) {
    int t = blockIdx.x * blockDim.x + threadIdx.x;
    int base = t * 4;
    if (base + 3 < E) {
        int4 s = *(const int4*)(src + base);
        int4 d = *(const int4*)(dst + base);
        int p;
        p = offset[d.x] + atomicAdd(&cursor[d.x], 1); csr_src[p] = s.x;
        p = offset[d.y] + atomicAdd(&cursor[d.y], 1); csr_src[p] = s.y;
        p = offset[d.z] + atomicAdd(&cursor[d.z], 1); csr_src[p] = s.z;
        p = offset[d.w] + atomicAdd(&cursor[d.w], 1); csr_src[p] = s.w;
    } else {
        for (int i = base; i < E; ++i) {
            int d = dst[i];
            int p = offset[d] + atomicAdd(&cursor[d], 1);
            csr_src[p] = src[i];
        }
    }
}

__global__ void scatter_kernel(const float* __restrict__ h,
                               const int* __restrict__ src, const int* __restrict__ dst,
                               const float* __restrict__ norm_src,
                               float* __restrict__ out, int E) {
    long long t = (long long)blockIdx.x * blockDim.x + threadIdx.x;
    int e = (int)(t >> 6);
    if (e >= E) return;
    int j = (int)(t & 63);
    int s = src[e];
    float v = h[s * D + j] * norm_src[s];
    unsafeAtomicAdd(&out[dst[e] * D + j], v);
}

__global__ void scale_kernel(float* __restrict__ out, const int* __restrict__ deg_dst, int n) {
    int t = blockIdx.x * blockDim.x + threadIdx.x;
    if (t < n) {
        int dg = deg_dst[t >> 6]; if (dg < 1) dg = 1;
        out[t] *= 1.0f / (float)dg;
    }
}

static inline size_t align16(size_t x) { return (x + 15) & ~(size_t)15; }

extern "C" void kernel_launch(void* const* d_in, const int* in_sizes, int n_in,
                              void* d_out, int out_size, void* d_ws, size_t ws_size,
                              hipStream_t stream) {
    const float* h   = (const float*)d_in[0];
    const int*   src = (const int*)d_in[1];
    const int*   dst = (const int*)d_in[2];
    float* out = (float*)d_out;

    const int E     = in_sizes[1];
    const int n_src = in_sizes[0] / D;
    const int n_dst = out_size / D;
    const int n_scan = 2 * NBUCK * NCHUNK;
    const int epc = (E + NCHUNK - 1) / NCHUNK;

    // ---- Path A: sort + bf16-feat precompute + 16-deep gather ----
    char* w = (char*)d_ws;
    size_t off = 0;
    size_t o_cnt   = off; off = align16(off + (size_t)n_scan * 4);
    size_t o_btot  = off; off = align16(off + (size_t)(2 * NBUCK) * 4);
    size_t o_packD = off; off = align16(off + (size_t)E * 4);
    size_t o_csr   = off; off = align16(off + (size_t)E * 4);
    size_t o_od    = off; off = align16(off + (size_t)n_dst * 8);
    size_t o_feat  = off; off = align16(off + (size_t)n_src * 64 * 2);
    size_t o_srtS  = off; off = align16(off + (size_t)E);
    size_t needA = off;

    if (ws_size >= needA && n_src <= NBUCK * 128 && n_dst <= NBUCK * 128 &&
        epc <= (1 << 20)) {
        int* cnt    = (int*)(w + o_cnt);
        int* btot   = (int*)(w + o_btot);
        int* packD  = (int*)(w + o_packD);
        int* csr    = (int*)(w + o_csr);
        int2* od    = (int2*)(w + o_od);
        unsigned short* featb = (unsigned short*)(w + o_feat);
        unsigned char* srtS   = (unsigned char*)(w + o_srtS);

        p1_count<<<NCHUNK, 256, 0, stream>>>(src, dst, E, epc, cnt);
        scanA_kernel<<<2 * NBUCK, 256, 0, stream>>>(cnt, btot);
        scanB_kernel<<<1, 1024, 0, stream>>>(btot);
        p2_scatter<<<NCHUNK, 256, 0, stream>>>(src, dst, E, epc, cnt, btot, packD, srtS);
        p3_merged<<<2 * NBUCK, 256, 0, stream>>>(packD, srtS, btot, (const float4*)h,
                                                 E, n_dst, n_src, csr, od, featb);
        long long gthreads = (long long)n_dst * D;
        gather_feat<<<(int)((gthreads + 255) / 256), 256, 0, stream>>>(
            featb, csr, od, (float4*)out, n_dst);
        return;
    }

    // ---- Path A2: R5 pipeline (f32 h gather, no feat buffer) ----
    size_t needA2 = ((size_t)n_scan + 2 * NBUCK + 2 * (size_t)E
                     + 2 * (size_t)n_dst + n_src) * 4 + (size_t)E;
    if (ws_size >= needA2 && n_src <= NBUCK * 128 && n_dst <= NBUCK * 128) {
        int* cnt    = (int*)d_ws;
        int* btot   = cnt + n_scan;
        int* packD  = btot + 2 * NBUCK;
        int* csr    = packD + E;
        int* deg    = csr + E;
        int* offset = deg + n_dst;
        float* norm_src = (float*)(offset + n_dst);
        unsigned char* srtS = (unsigned char*)(norm_src + n_src);

        p1_count<<<NCHUNK, 256, 0, stream>>>(src, dst, E, epc, cnt);
        scanA_kernel<<<2 * NBUCK, 256, 0, stream>>>(cnt, btot);
        scanB_kernel<<<1, 1024, 0, stream>>>(btot);
        p2_scatter<<<NCHUNK, 256, 0, stream>>>(src, dst, E, epc, cnt, btot, packD, srtS);
        p3_place<<<NBUCK, 256, 0, stream>>>(packD, btot, E, n_dst, csr, offset, deg);
        p3s_norm<<<NBUCK, 256, 0, stream>>>(srtS, btot, E, n_src, norm_src);
        long long gthreads = (long long)n_dst * D;
        gather_kernel<<<(int)((gthreads + 255) / 256), 256, 0, stream>>>(
            (const float4*)h, csr, offset, deg, norm_src, (float4*)out, n_dst);
        return;
    }

    // ---- Path B: CSR via device atomics ----
    const int nbB = (n_dst + SCAN_B - 1) / SCAN_B;
    const int nbB_pad = ((nbB + 1023) / 1024) * 1024;
    const int eb4 = (E + 4 * 256 - 1) / (4 * 256);
    const int nblk = ((n_src > n_dst ? n_src : n_dst) + 255) / 256;
    size_t needB = ((size_t)n_src * 2 + (size_t)n_dst * 3 + nbB_pad) * 4 + (size_t)E * 4;

    if (ws_size >= needB) {
        int* deg_src = (int*)d_ws;
        int* deg_dst = deg_src + n_src;
        int* cursor  = deg_dst + n_dst;
        int* offset  = cursor + n_dst;
        int* bsums   = offset + n_dst;
        float* norm_src = (float*)(bsums + nbB_pad);
        int* csr_src = (int*)(norm_src + n_src);

        hipMemsetAsync(d_ws, 0, sizeof(int) * (size_t)(n_src + 2 * (size_t)n_dst), stream);
        degree_kernel<<<eb4, 256, 0, stream>>>(src, dst, E, deg_src, deg_dst);
        norm_src_kernel<<<nblk, 256, 0, stream>>>(deg_src, n_src, norm_src);
        scan1_kernel<<<nbB, SCAN_B, 0, stream>>>(deg_dst, n_dst, offset, bsums);
        scan2_kernel<<<1, 1024, 0, stream>>>(bsums, nbB);
        scan3_kernel<<<nbB, SCAN_B, 0, stream>>>(offset, bsums, n_dst);
        fill_kernel<<<eb4, 256, 0, stream>>>(src, dst, E, offset, cursor, csr_src);
        long long gthreads = (long long)n_dst * D;
        gather_kernel<<<(int)((gthreads + 255) / 256), 256, 0, stream>>>(
            (const float4*)h, csr_src, offset, deg_dst, norm_src, (float4*)out, n_dst);
        return;
    }

    // ---- Path C: minimal atomic scatter ----
    {
        int* deg_src = (int*)d_ws;
        int* deg_dst = deg_src + n_src;
        float* norm_src = (float*)(deg_dst + n_dst);
        hipMemsetAsync(d_ws, 0, sizeof(int) * (size_t)(n_src + n_dst), stream);
        hipMemsetAsync(d_out, 0, sizeof(float) * (size_t)out_size, stream);
        degree_kernel<<<eb4, 256, 0, stream>>>(src, dst, E, deg_src, deg_dst);
        norm_src_kernel<<<nblk, 256, 0, stream>>>(deg_src, n_src, norm_src);
        long long total = (long long)E * D;
        scatter_kernel<<<(int)((total + 255) / 256), 256, 0, stream>>>(h, src, dst, norm_src, out, E);
        scale_kernel<<<(out_size + 255) / 256, 256, 0, stream>>>(out, deg_dst, out_size);
    }
}

// Round 8
// 103.971 us; speedup vs baseline: 4.8560x; 1.2397x over previous
//
#include <hip/hip_runtime.h>

#define D 64
#define SCAN_B 256
#define NBUCK 256    // coarse buckets: key >> 9
#define BSH 9
#define BMSK 511     // second-level bins per bucket
#define NCHUNK 256   // edge chunks for count/scatter passes

typedef __attribute__((ext_vector_type(8))) unsigned short ushort8_t;

__device__ __forceinline__ unsigned short f2bf(float f) {
    unsigned u = __float_as_uint(f);
    unsigned r = (u + 0x7FFFu + ((u >> 16) & 1u)) >> 16;   // RNE
    return (unsigned short)r;
}

// ================= Path A: atomic-free two-level counting sort =================

// P1: per (bucket, chunk) counts for dst and src, bucket-major layout. 512 thr.
__global__ void p1_count(const int* __restrict__ src, const int* __restrict__ dst, int E,
                         int epc, int* __restrict__ cnt) {
    __shared__ int cd[NBUCK], cs[NBUCK];
    int c = blockIdx.x;
    for (int i = threadIdx.x; i < NBUCK; i += blockDim.x) { cd[i] = 0; cs[i] = 0; }
    __syncthreads();
    int beg = c * epc, end = min(E, beg + epc);
    for (int i = beg + threadIdx.x; i < end; i += blockDim.x) {
        atomicAdd(&cd[((unsigned)dst[i]) >> BSH], 1);
        atomicAdd(&cs[((unsigned)src[i]) >> BSH], 1);
    }
    __syncthreads();
    for (int b = threadIdx.x; b < NBUCK; b += blockDim.x) {
        cnt[(size_t)b * NCHUNK + c] = cd[b];
        cnt[(size_t)(NBUCK + b) * NCHUNK + c] = cs[b];
    }
}

// scanA: one block per bucket-row (2*NBUCK rows): exclusive scan of NCHUNK counts
// in place; row total -> btot[row]. 256 threads, 1 entry each.
__global__ void scanA_kernel(int* __restrict__ cnt, int* __restrict__ btot) {
    __shared__ int lds[NCHUNK];
    int g = blockIdx.x;
    int* e = cnt + (size_t)g * NCHUNK;
    int t = threadIdx.x;
    int v = e[t];
    lds[t] = v;
    __syncthreads();
    for (int off = 1; off < NCHUNK; off <<= 1) {
        int add = (t >= off) ? lds[t - off] : 0;
        __syncthreads();
        lds[t] += add;
        __syncthreads();
    }
    int incl = lds[t];
    e[t] = incl - v;                 // exclusive
    if (t == NCHUNK - 1) btot[g] = incl;
}

// scanB: exclusive scan of the 2*NBUCK row totals in place (1 block, 256 thr x 2).
__global__ void scanB_kernel(int* __restrict__ btot) {
    __shared__ int lds[NBUCK];      // 256 pairs cover 512 entries
    int t = threadIdx.x;
    int a0 = btot[2 * t], a1 = btot[2 * t + 1];
    int p = a0 + a1;
    lds[t] = p;
    __syncthreads();
    for (int off = 1; off < 256; off <<= 1) {
        int v = (t >= off) ? lds[t - off] : 0;
        __syncthreads();
        lds[t] += v;
        __syncthreads();
    }
    int incl = lds[t];
    int excl = incl - p;
    btot[2 * t] = excl;
    btot[2 * t + 1] = excl + a0;
}

// P2: scatter edges into bucket-partitioned arrays via LDS cursors. 512 thr.
__global__ void p2_scatter(const int* __restrict__ src, const int* __restrict__ dst, int E,
                           int epc, const int* __restrict__ cnt, const int* __restrict__ btot,
                           int* __restrict__ packD, unsigned short* __restrict__ srtS) {
    __shared__ int curD[NBUCK], curS[NBUCK];
    int c = blockIdx.x;
    for (int b = threadIdx.x; b < NBUCK; b += blockDim.x) {
        curD[b] = btot[b] + cnt[(size_t)b * NCHUNK + c];
        curS[b] = btot[NBUCK + b] + cnt[(size_t)(NBUCK + b) * NCHUNK + c] - E;
    }
    __syncthreads();
    int beg = c * epc, end = min(E, beg + epc);
    for (int i = beg + threadIdx.x; i < end; i += blockDim.x) {
        int d = dst[i], s = src[i];
        int pd = atomicAdd(&curD[((unsigned)d) >> BSH], 1);
        packD[pd] = (s << BSH) | (d & BMSK);
        int ps = atomicAdd(&curS[((unsigned)s) >> BSH], 1);
        srtS[ps] = (unsigned short)(s & BMSK);
    }
}

// P3 merged: blocks [0,NBUCK) place dst CSR (512-bin hist + pair scan);
// blocks [NBUCK,2*NBUCK) compute src norms AND write feat(bf16)=h*norm.
__global__ void p3_merged(const int* __restrict__ packD, const unsigned short* __restrict__ srtS,
                          const int* __restrict__ btot, const float4* __restrict__ h4,
                          int E, int n_dst, int n_src,
                          int* __restrict__ csr, int2* __restrict__ od_arr,
                          unsigned short* __restrict__ featb) {
    __shared__ int hist[512];
    __shared__ int scan_s[256];
    __shared__ float nrm[512];
    int blk = blockIdx.x;
    int t = threadIdx.x;
    if (blk < NBUCK) {
        int b = blk;
        int beg = btot[b];
        int end = btot[b + 1];          // btot[NBUCK] == E
        hist[t] = 0; hist[t + 256] = 0;
        __syncthreads();
        for (int i = beg + t; i < end; i += 256)
            atomicAdd(&hist[packD[i] & BMSK], 1);
        __syncthreads();
        // pair-scan over 512 bins: thread t owns bins 2t, 2t+1
        int a0 = hist[2 * t], a1 = hist[2 * t + 1];
        int p = a0 + a1;
        scan_s[t] = p;
        __syncthreads();
        for (int off = 1; off < 256; off <<= 1) {
            int v = (t >= off) ? scan_s[t - off] : 0;
            __syncthreads();
            scan_s[t] += v;
            __syncthreads();
        }
        int e0 = scan_s[t] - p;         // exclusive prefix of bin 2t
        int dbin0 = b * 512 + 2 * t;
        int dbin1 = dbin0 + 1;
        if (dbin0 < n_dst) od_arr[dbin0] = make_int2(beg + e0, a0);
        if (dbin1 < n_dst) od_arr[dbin1] = make_int2(beg + e0 + a0, a1);
        hist[2 * t] = e0;               // becomes cursor
        hist[2 * t + 1] = e0 + a0;
        __syncthreads();
        for (int i = beg + t; i < end; i += 256) {
            int v = packD[i];
            int pos = beg + atomicAdd(&hist[v & BMSK], 1);
            csr[pos] = v >> BSH;
        }
    } else {
        int row = blk;                  // NBUCK..2*NBUCK-1
        int b = blk - NBUCK;
        int beg = btot[row] - E;
        int end = ((row + 1 < 2 * NBUCK) ? btot[row + 1] : 2 * E) - E;
        hist[t] = 0; hist[t + 256] = 0;
        __syncthreads();
        for (int i = beg + t; i < end; i += 256)
            atomicAdd(&hist[srtS[i]], 1);
        __syncthreads();
        {
            int h0 = hist[t];       if (h0 < 1) h0 = 1;
            int h1 = hist[t + 256]; if (h1 < 1) h1 = 1;
            nrm[t] = 1.0f / (float)h0;
            nrm[t + 256] = 1.0f / (float)h1;
        }
        __syncthreads();
        for (int i = t; i < 512 * 8; i += 256) {
            int r = i >> 3, l8 = i & 7;
            int gsrc = b * 512 + r;
            if (gsrc < n_src) {
                float nm = nrm[r];
                float4 v0 = h4[(size_t)gsrc * 16 + l8 * 2];
                float4 v1 = h4[(size_t)gsrc * 16 + l8 * 2 + 1];
                ushort8_t o;
                o[0] = f2bf(v0.x * nm); o[1] = f2bf(v0.y * nm);
                o[2] = f2bf(v0.z * nm); o[3] = f2bf(v0.w * nm);
                o[4] = f2bf(v1.x * nm); o[5] = f2bf(v1.y * nm);
                o[6] = f2bf(v1.z * nm); o[7] = f2bf(v1.w * nm);
                *(ushort8_t*)(featb + (size_t)gsrc * 64 + l8 * 8) = o;
            }
        }
    }
}

// gather: one wave per dst row; 8 edge-groups x 8 lanes x ushort8 (bf16 feat),
// unrolled 2x -> 16 edges in flight per wave.
__global__ void gather_feat(const unsigned short* __restrict__ featb,
                            const int* __restrict__ csr,
                            const int2* __restrict__ od_arr,
                            float4* __restrict__ out4, int n_dst) {
    int gid = blockIdx.x * blockDim.x + threadIdx.x;
    int row = gid >> 6;
    if (row >= n_dst) return;
    int lane = threadIdx.x & 63;
    int g = lane >> 3;       // edge group 0..7
    int l8 = lane & 7;       // ushort8 slot within 64-elem row
    int2 od = od_arr[row];
    int beg = od.x, dg = od.y;
    int end = beg + dg;
    float a[8] = {0.f, 0.f, 0.f, 0.f, 0.f, 0.f, 0.f, 0.f};
    for (int k = beg + g; k < end; k += 16) {
        int s0 = csr[k];
        ushort8_t v0 = *(const ushort8_t*)(featb + (size_t)s0 * 64 + l8 * 8);
        int k2 = k + 8;
        if (k2 < end) {
            int s1 = csr[k2];
            ushort8_t v1 = *(const ushort8_t*)(featb + (size_t)s1 * 64 + l8 * 8);
            #pragma unroll
            for (int j = 0; j < 8; ++j)
                a[j] += __uint_as_float(((unsigned)v0[j]) << 16)
                      + __uint_as_float(((unsigned)v1[j]) << 16);
        } else {
            #pragma unroll
            for (int j = 0; j < 8; ++j)
                a[j] += __uint_as_float(((unsigned)v0[j]) << 16);
        }
    }
    #pragma unroll
    for (int m = 8; m < 64; m <<= 1) {
        #pragma unroll
        for (int j = 0; j < 8; ++j) a[j] += __shfl_xor(a[j], m);
    }
    if (g == 0) {
        float nd = 1.0f / (float)(dg < 1 ? 1 : dg);
        float4 r0, r1;
        r0.x = a[0] * nd; r0.y = a[1] * nd; r0.z = a[2] * nd; r0.w = a[3] * nd;
        r1.x = a[4] * nd; r1.y = a[5] * nd; r1.z = a[6] * nd; r1.w = a[7] * nd;
        out4[(size_t)row * 16 + l8 * 2]     = r0;
        out4[(size_t)row * 16 + l8 * 2 + 1] = r1;
    }
}

// ====================== legacy kernels (paths B/C) ======================
__global__ void scan1_kernel(const int* __restrict__ deg, int n,
                             int* __restrict__ out, int* __restrict__ bsums) {
    __shared__ int tmp[SCAN_B];
    int t = blockIdx.x * SCAN_B + threadIdx.x;
    int v = (t < n) ? deg[t] : 0;
    tmp[threadIdx.x] = v;
    __syncthreads();
    for (int off = 1; off < SCAN_B; off <<= 1) {
        int add = (threadIdx.x >= off) ? tmp[threadIdx.x - off] : 0;
        __syncthreads();
        tmp[threadIdx.x] += add;
        __syncthreads();
    }
    if (t < n) out[t] = tmp[threadIdx.x] - v;
    if (threadIdx.x == SCAN_B - 1) bsums[blockIdx.x] = tmp[threadIdx.x];
}

__global__ void scan2_kernel(int* __restrict__ bsums, int nb) {
    __shared__ int tmp[1024];
    __shared__ int carry_s;
    if (threadIdx.x == 0) carry_s = 0;
    __syncthreads();
    for (int base = 0; base < nb; base += 1024) {
        int i = base + threadIdx.x;
        int v = (i < nb) ? bsums[i] : 0;
        tmp[threadIdx.x] = v;
        __syncthreads();
        for (int off = 1; off < 1024; off <<= 1) {
            int add = (threadIdx.x >= off) ? tmp[threadIdx.x - off] : 0;
            __syncthreads();
            tmp[threadIdx.x] += add;
            __syncthreads();
        }
        int incl = tmp[threadIdx.x];
        int carry = carry_s;
        if (i < nb) bsums[i] = incl - v + carry;
        __syncthreads();
        if (threadIdx.x == 0) carry_s = carry + tmp[1023];
        __syncthreads();
    }
}

__global__ void scan3_kernel(int* __restrict__ out, const int* __restrict__ bsums, int n) {
    int t = blockIdx.x * SCAN_B + threadIdx.x;
    if (t < n) out[t] += bsums[blockIdx.x];
}

__global__ void gather_kernel(const float4* __restrict__ h4, const int* __restrict__ csr_src,
                              const int* __restrict__ offset, const int* __restrict__ deg_dst,
                              const float* __restrict__ norm_src,
                              float4* __restrict__ out4, int n_dst) {
    int gid = blockIdx.x * blockDim.x + threadIdx.x;
    int row = gid >> 6;
    if (row >= n_dst) return;
    int lane = threadIdx.x & 63;
    int g = lane >> 4;
    int l16 = lane & 15;
    int beg = offset[row];
    int deg = deg_dst[row];
    int end = beg + deg;
    float ax = 0.f, ay = 0.f, az = 0.f, aw = 0.f;
    for (int k = beg + g; k < end; k += 4) {
        int s = csr_src[k];
        float ns = norm_src[s];
        float4 v = h4[s * 16 + l16];
        ax = fmaf(v.x, ns, ax);
        ay = fmaf(v.y, ns, ay);
        az = fmaf(v.z, ns, az);
        aw = fmaf(v.w, ns, aw);
    }
    ax += __shfl_xor(ax, 16); ay += __shfl_xor(ay, 16);
    az += __shfl_xor(az, 16); aw += __shfl_xor(aw, 16);
    ax += __shfl_xor(ax, 32); ay += __shfl_xor(ay, 32);
    az += __shfl_xor(az, 32); aw += __shfl_xor(aw, 32);
    if (g == 0) {
        int dg = deg < 1 ? 1 : deg;
        float nd = 1.0f / (float)dg;
        float4 r;
        r.x = ax * nd; r.y = ay * nd; r.z = az * nd; r.w = aw * nd;
        out4[row * 16 + l16] = r;
    }
}

__global__ void degree_kernel(const int* __restrict__ src, const int* __restrict__ dst,
                              int E, int* __restrict__ deg_src, int* __restrict__ deg_dst) {
    int t = blockIdx.x * blockDim.x + threadIdx.x;
    int base = t * 4;
    if (base + 3 < E) {
        int4 s = *(const int4*)(src + base);
        int4 d = *(const int4*)(dst + base);
        atomicAdd(&deg_src[s.x], 1); atomicAdd(&deg_src[s.y], 1);
        atomicAdd(&deg_src[s.z], 1); atomicAdd(&deg_src[s.w], 1);
        atomicAdd(&deg_dst[d.x], 1); atomicAdd(&deg_dst[d.y], 1);
        atomicAdd(&deg_dst[d.z], 1); atomicAdd(&deg_dst[d.w], 1);
    } else {
        for (int i = base; i < E; ++i) {
            atomicAdd(&deg_src[src[i]], 1);
            atomicAdd(&deg_dst[dst[i]], 1);
        }
    }
}

__global__ void norm_src_kernel(const int* __restrict__ deg_src, int n_src,
                                float* __restrict__ norm_src) {
    int t = blockIdx.x * blockDim.x + threadIdx.x;
    if (t < n_src) {
        int s = deg_src[t]; if (s < 1) s = 1;
        norm_src[t] = 1.0f / (float)s;
    }
}

__global__ void fill_kernel(const int* __restrict__ src, const int* __restrict__ dst, int E,
                            const int* __restrict__ offset, int* __restrict__ cursor,
                            int* __restrict__ csr_src) {
    int t = blockIdx.x * blockDim.x + threadIdx.x;
    int base = t * 4;
    if (base + 3 < E) {
        int4 s = *(const int4*)(src + base);
        int4 d = *(const int4*)(dst + base);
        int p;
        p = offset[d.x] + atomicAdd(&cursor[d.x], 1); csr_src[p] = s.x;
        p = offset[d.y] + atomicAdd(&cursor[d.y], 1); csr_src[p] = s.y;
        p = offset[d.z] + atomicAdd(&cursor[d.z], 1); csr_src[p] = s.z;
        p = offset[d.w] + atomicAdd(&cursor[d.w], 1); csr_src[p] = s.w;
    } else {
        for (int i = base; i < E; ++i) {
            int d = dst[i];
            int p = offset[d] + atomicAdd(&cursor[d], 1);
            csr_src[p] = src[i];
        }
    }
}

__global__ void scatter_kernel(const float* __restrict__ h,
                               const int* __restrict__ src, const int* __restrict__ dst,
                               const float* __restrict__ norm_src,
                               float* __restrict__ out, int E) {
    long long t = (long long)blockIdx.x * blockDim.x + threadIdx.x;
    int e = (int)(t >> 6);
    if (e >= E) return;
    int j = (int)(t & 63);
    int s = src[e];
    float v = h[s * D + j] * norm_src[s];
    unsafeAtomicAdd(&out[dst[e] * D + j], v);
}

__global__ void scale_kernel(float* __restrict__ out, const int* __restrict__ deg_dst, int n) {
    int t = blockIdx.x * blockDim.x + threadIdx.x;
    if (t < n) {
        int dg = deg_dst[t >> 6]; if (dg < 1) dg = 1;
        out[t] *= 1.0f / (float)dg;
    }
}

static inline size_t align16(size_t x) { return (x + 15) & ~(size_t)15; }

extern "C" void kernel_launch(void* const* d_in, const int* in_sizes, int n_in,
                              void* d_out, int out_size, void* d_ws, size_t ws_size,
                              hipStream_t stream) {
    const float* h   = (const float*)d_in[0];
    const int*   src = (const int*)d_in[1];
    const int*   dst = (const int*)d_in[2];
    float* out = (float*)d_out;

    const int E     = in_sizes[1];
    const int n_src = in_sizes[0] / D;
    const int n_dst = out_size / D;
    const int n_cnt = 2 * NBUCK * NCHUNK;            // 131072
    const int epc = (E + NCHUNK - 1) / NCHUNK;

    // ---- Path A: radix-256/512 sort + bf16-feat precompute + 16-deep gather ----
    char* w = (char*)d_ws;
    size_t off = 0;
    size_t o_cnt   = off; off = align16(off + (size_t)n_cnt * 4);
    size_t o_btot  = off; off = align16(off + (size_t)(2 * NBUCK) * 4);
    size_t o_packD = off; off = align16(off + (size_t)E * 4);
    size_t o_csr   = off; off = align16(off + (size_t)E * 4);
    size_t o_od    = off; off = align16(off + (size_t)n_dst * 8);
    size_t o_feat  = off; off = align16(off + (size_t)n_src * 64 * 2);
    size_t o_srtS  = off; off = align16(off + (size_t)E * 2);
    size_t needA = off;

    if (ws_size >= needA && n_src <= NBUCK * 512 && n_dst <= NBUCK * 512) {
        int* cnt    = (int*)(w + o_cnt);
        int* btot   = (int*)(w + o_btot);
        int* packD  = (int*)(w + o_packD);
        int* csr    = (int*)(w + o_csr);
        int2* od    = (int2*)(w + o_od);
        unsigned short* featb = (unsigned short*)(w + o_feat);
        unsigned short* srtS  = (unsigned short*)(w + o_srtS);

        p1_count<<<NCHUNK, 512, 0, stream>>>(src, dst, E, epc, cnt);
        scanA_kernel<<<2 * NBUCK, NCHUNK, 0, stream>>>(cnt, btot);
        scanB_kernel<<<1, 256, 0, stream>>>(btot);
        p2_scatter<<<NCHUNK, 512, 0, stream>>>(src, dst, E, epc, cnt, btot, packD, srtS);
        p3_merged<<<2 * NBUCK, 256, 0, stream>>>(packD, srtS, btot, (const float4*)h,
                                                 E, n_dst, n_src, csr, od, featb);
        long long gthreads = (long long)n_dst * D;
        gather_feat<<<(int)((gthreads + 255) / 256), 256, 0, stream>>>(
            featb, csr, od, (float4*)out, n_dst);
        return;
    }

    // ---- Path B: CSR via device atomics ----
    const int nbB = (n_dst + SCAN_B - 1) / SCAN_B;
    const int nbB_pad = ((nbB + 1023) / 1024) * 1024;
    const int eb4 = (E + 4 * 256 - 1) / (4 * 256);
    const int nblk = ((n_src > n_dst ? n_src : n_dst) + 255) / 256;
    size_t needB = ((size_t)n_src * 2 + (size_t)n_dst * 3 + nbB_pad) * 4 + (size_t)E * 4;

    if (ws_size >= needB) {
        int* deg_src = (int*)d_ws;
        int* deg_dst = deg_src + n_src;
        int* cursor  = deg_dst + n_dst;
        int* offset  = cursor + n_dst;
        int* bsums   = offset + n_dst;
        float* norm_src = (float*)(bsums + nbB_pad);
        int* csr_src = (int*)(norm_src + n_src);

        hipMemsetAsync(d_ws, 0, sizeof(int) * (size_t)(n_src + 2 * (size_t)n_dst), stream);
        degree_kernel<<<eb4, 256, 0, stream>>>(src, dst, E, deg_src, deg_dst);
        norm_src_kernel<<<nblk, 256, 0, stream>>>(deg_src, n_src, norm_src);
        scan1_kernel<<<nbB, SCAN_B, 0, stream>>>(deg_dst, n_dst, offset, bsums);
        scan2_kernel<<<1, 1024, 0, stream>>>(bsums, nbB);
        scan3_kernel<<<nbB, SCAN_B, 0, stream>>>(offset, bsums, n_dst);
        fill_kernel<<<eb4, 256, 0, stream>>>(src, dst, E, offset, cursor, csr_src);
        long long gthreads = (long long)n_dst * D;
        gather_kernel<<<(int)((gthreads + 255) / 256), 256, 0, stream>>>(
            (const float4*)h, csr_src, offset, deg_dst, norm_src, (float4*)out, n_dst);
        return;
    }

    // ---- Path C: minimal atomic scatter ----
    {
        int* deg_src = (int*)d_ws;
        int* deg_dst = deg_src + n_src;
        float* norm_src = (float*)(deg_dst + n_dst);
        hipMemsetAsync(d_ws, 0, sizeof(int) * (size_t)(n_src + n_dst), stream);
        hipMemsetAsync(d_out, 0, sizeof(float) * (size_t)out_size, stream);
        degree_kernel<<<eb4, 256, 0, stream>>>(src, dst, E, deg_src, deg_dst);
        norm_src_kernel<<<nblk, 256, 0, stream>>>(deg_src, n_src, norm_src);
        long long total = (long long)E * D;
        scatter_kernel<<<(int)((total + 255) / 256), 256, 0, stream>>>(h, src, dst, norm_src, out, E);
        scale_kernel<<<(out_size + 255) / 256, 256, 0, stream>>>(out, deg_dst, out_size);
    }
}